// Round 2
// baseline (1518.561 us; speedup 1.0000x reference)
//
#include <hip/hip_runtime.h>
#include <hip/hip_bf16.h>
#include <cstddef>
#include <cstdint>

#define N_NODESC 100000
#define N_EDGESC 500000
#define NBATCH   512
#define SCAN_CHUNK 1024

static inline int divup(int a, int b) { return (a + b - 1) / b; }

typedef __hip_bfloat16 bf16;

__device__ inline float ldf(const float* p) { return *p; }
__device__ inline float ldf(const bf16* p) { return __bfloat162float(*p); }
__device__ inline void stf(float* p, float v) { *p = v; }
__device__ inline void stf(bf16* p, float v) { *p = __float2bfloat16(v); }

// ---------------- zero ints ----------------
__global__ void zero_ints(int* __restrict__ p, int n) {
    int i = blockIdx.x * blockDim.x + threadIdx.x;
    if (i < n) p[i] = 0;
}

// ---------------- degree / dinv ----------------
__global__ void count_deg(const int* __restrict__ dst, int* __restrict__ deg, int e) {
    int i = blockIdx.x * blockDim.x + threadIdx.x;
    if (i < e) atomicAdd(&deg[dst[i]], 1);
}

__global__ void compute_dinv(const int* __restrict__ deg, float* __restrict__ dinv, int n) {
    int i = blockIdx.x * blockDim.x + threadIdx.x;
    if (i < n) dinv[i] = 1.0f / sqrtf((float)deg[i] + 1.0f);
}

// ---------------- exclusive scan (3-phase) ----------------
__global__ void scan_chunks(const int* __restrict__ deg, int* __restrict__ out,
                            int* __restrict__ sums, int n) {
    __shared__ int sdata[256];
    int t = threadIdx.x;
    int base = blockIdx.x * SCAN_CHUNK;
    int v[4];
    int s = 0;
#pragma unroll
    for (int j = 0; j < 4; ++j) {
        int idx = base + t * 4 + j;
        v[j] = s;
        int d = (idx < n) ? deg[idx] : 0;
        s += d;
    }
    int x = s;
    sdata[t] = x;
    __syncthreads();
    for (int off = 1; off < 256; off <<= 1) {
        int y = (t >= off) ? sdata[t - off] : 0;
        __syncthreads();
        x += y;
        sdata[t] = x;
        __syncthreads();
    }
    int thread_excl = x - s;
    if (t == 255) sums[blockIdx.x] = x;
#pragma unroll
    for (int j = 0; j < 4; ++j) {
        int idx = base + t * 4 + j;
        if (idx < n) out[idx] = thread_excl + v[j];
    }
}

__global__ void scan_sums(int* sums, int nchunks) {
    if (threadIdx.x == 0 && blockIdx.x == 0) {
        int acc = 0;
        for (int i = 0; i < nchunks; ++i) { int v = sums[i]; sums[i] = acc; acc += v; }
    }
}

__global__ void finalize_rowptr(int* __restrict__ row_ptr, const int* __restrict__ sums,
                                int* __restrict__ fill, int n, int e) {
    int i = blockIdx.x * blockDim.x + threadIdx.x;
    if (i < n) {
        int v = row_ptr[i] + sums[i / SCAN_CHUNK];
        row_ptr[i] = v;
        fill[i] = v;
    }
    if (i == 0) row_ptr[n] = e;
}

__global__ void fill_csr(const int* __restrict__ src, const int* __restrict__ dst,
                         int* __restrict__ fill, int* __restrict__ csr_src, int e) {
    int i = blockIdx.x * blockDim.x + threadIdx.x;
    if (i < e) {
        int d = dst[i];
        int pos = atomicAdd(&fill[d], 1);
        csr_src[pos] = src[i];
    }
}

// ---------------- batch segment pointers (batch is sorted) ----------------
__global__ void build_batch_ptr(const int* __restrict__ batch, int* __restrict__ bptr,
                                int n, int nb) {
    int i = blockIdx.x * blockDim.x + threadIdx.x;
    if (i >= n) return;
    int b = batch[i];
    int prev = (i == 0) ? -1 : batch[i - 1];
    for (int bb = prev + 1; bb <= b; ++bb) bptr[bb] = i;
    if (i == n - 1) {
        for (int bb = b + 1; bb <= nb; ++bb) bptr[bb] = n;
    }
}

// ---------------- generic tiled GEMM: C[n,KO] = A[n,KI] @ W[KI,KO] (+bias)(+relu) ----------------
// TA: input element type (float or bf16); TC: output element type. fp32 compute.
template <int KI, int KO, bool RELU, bool BIAS, typename TA, typename TC>
__global__ __launch_bounds__(256) void gemm_tiled(const TA* __restrict__ A,
                                                  const float* __restrict__ W,
                                                  const float* __restrict__ bias,
                                                  TC* __restrict__ C,
                                                  int n, int ldc, int col_off) {
    __shared__ float sA[16][65];
    __shared__ float sW[16][65];
    const int tid = threadIdx.x;
    const int tr = tid >> 4, tc = tid & 15;
    const int row0 = blockIdx.x * 64;
    const int col0 = blockIdx.y * 64;
    float acc[4][4] = {};
    for (int k0 = 0; k0 < KI; k0 += 16) {
        {
            int r = tid >> 4;
            int kk = tid & 15;
#pragma unroll
            for (int i = 0; i < 4; ++i) {
                int rr = r + 16 * i;
                int grow = row0 + rr;
                float v = 0.f;
                if (grow < n && (k0 + kk) < KI) v = ldf(&A[(size_t)grow * KI + k0 + kk]);
                sA[kk][rr] = v;
            }
        }
        {
            int kk = tid >> 6;
            int c = tid & 63;
#pragma unroll
            for (int i = 0; i < 4; ++i) {
                int kkk = kk + 4 * i;
                float v = 0.f;
                if ((k0 + kkk) < KI && (col0 + c) < KO) v = W[(size_t)(k0 + kkk) * KO + col0 + c];
                sW[kkk][c] = v;
            }
        }
        __syncthreads();
#pragma unroll
        for (int k = 0; k < 16; ++k) {
            float a0 = sA[k][tr], a1 = sA[k][tr + 16], a2 = sA[k][tr + 32], a3 = sA[k][tr + 48];
            float w0 = sW[k][tc], w1 = sW[k][tc + 16], w2 = sW[k][tc + 32], w3 = sW[k][tc + 48];
            acc[0][0] = fmaf(a0, w0, acc[0][0]); acc[0][1] = fmaf(a0, w1, acc[0][1]);
            acc[0][2] = fmaf(a0, w2, acc[0][2]); acc[0][3] = fmaf(a0, w3, acc[0][3]);
            acc[1][0] = fmaf(a1, w0, acc[1][0]); acc[1][1] = fmaf(a1, w1, acc[1][1]);
            acc[1][2] = fmaf(a1, w2, acc[1][2]); acc[1][3] = fmaf(a1, w3, acc[1][3]);
            acc[2][0] = fmaf(a2, w0, acc[2][0]); acc[2][1] = fmaf(a2, w1, acc[2][1]);
            acc[2][2] = fmaf(a2, w2, acc[2][2]); acc[2][3] = fmaf(a2, w3, acc[2][3]);
            acc[3][0] = fmaf(a3, w0, acc[3][0]); acc[3][1] = fmaf(a3, w1, acc[3][1]);
            acc[3][2] = fmaf(a3, w2, acc[3][2]); acc[3][3] = fmaf(a3, w3, acc[3][3]);
        }
        __syncthreads();
    }
#pragma unroll
    for (int i = 0; i < 4; ++i) {
        int grow = row0 + tr + 16 * i;
        if (grow >= n) continue;
#pragma unroll
        for (int j = 0; j < 4; ++j) {
            int gcol = col0 + tc + 16 * j;
            if (gcol >= KO) continue;
            float v = acc[i][j];
            if (BIAS) v += bias[gcol];
            if (RELU) v = fmaxf(v, 0.f);
            stf(&C[(size_t)grow * ldc + col_off + gcol], v);
        }
    }
}

// ---------------- GCN aggregation (gather over dst-CSR) + self loop + bias + relu ----------------
template <int F>
__global__ void gcn_gather_relu(const bf16* __restrict__ xw, const int* __restrict__ row_ptr,
                                const int* __restrict__ csr_src, const float* __restrict__ dinv,
                                const float* __restrict__ b, bf16* __restrict__ hout) {
    int node = blockIdx.x;
    int f = threadIdx.x;
    if (f >= F) return;
    float dn = dinv[node];
    int e0 = row_ptr[node], e1 = row_ptr[node + 1];
    float acc = __bfloat162float(xw[(size_t)node * F + f]) * dn * dn;
    for (int e = e0; e < e1; ++e) {
        int s = csr_src[e];
        acc = fmaf(__bfloat162float(xw[(size_t)s * F + f]), dinv[s] * dn, acc);
    }
    acc += b[f];
    hout[(size_t)node * F + f] = __float2bfloat16(fmaxf(acc, 0.f));
}

// ---------------- segment max pool (batch segments) ----------------
__global__ void seg_max(const bf16* __restrict__ h, const int* __restrict__ bptr,
                        float* __restrict__ g) {
    int b = blockIdx.x;
    int f = threadIdx.x;
    if (f >= 312) return;
    int n0 = bptr[b], n1 = bptr[b + 1];
    float m = -INFINITY;
    for (int n = n0; n < n1; ++n) m = fmaxf(m, __bfloat162float(h[(size_t)n * 312 + f]));
    g[(size_t)b * 312 + f] = m;
}

// ---------------- Conv1d(750->32, k=8, valid) over H=19 ----------------
__global__ __launch_bounds__(384) void conv1d_prot(const float* __restrict__ T,
                                                   const float* __restrict__ K,
                                                   const float* __restrict__ bxt,
                                                   float* __restrict__ outc) {
    __shared__ float sT[750 * 19];
    int b = blockIdx.x;
    for (int i = threadIdx.x; i < 750 * 19; i += blockDim.x)
        sT[i] = T[(size_t)b * (750 * 19) + i];
    __syncthreads();
    int o = threadIdx.x / 12, h = threadIdx.x % 12;
    if (o < 32) {
        float acc = 0.f;
        for (int i = 0; i < 750; ++i) {
            const float* kp = &K[(size_t)(o * 750 + i) * 8];
            const float* tp = &sT[i * 19 + h];
#pragma unroll
            for (int kh = 0; kh < 8; ++kh) acc = fmaf(tp[kh], kp[kh], acc);
        }
        outc[(size_t)b * 384 + o * 12 + h] = acc + bxt[o];
    }
}

// ---------------- final [512,512] @ [512,1] ----------------
__global__ void final_out(const float* __restrict__ f2, const float* __restrict__ Wo,
                          const float* __restrict__ bo, float* __restrict__ out) {
    int row = blockIdx.x * (blockDim.x / 64) + (threadIdx.x / 64);
    int lane = threadIdx.x & 63;
    if (row >= NBATCH) return;
    float acc = 0.f;
    for (int k = lane; k < 512; k += 64) acc = fmaf(f2[(size_t)row * 512 + k], Wo[k], acc);
#pragma unroll
    for (int off = 32; off > 0; off >>= 1) acc += __shfl_down(acc, off);
    if (lane == 0) out[row] = acc + bo[0];
}

extern "C" void kernel_launch(void* const* d_in, const int* in_sizes, int n_in,
                              void* d_out, int out_size, void* d_ws, size_t ws_size,
                              hipStream_t stream) {
    (void)in_sizes; (void)n_in; (void)out_size; (void)ws_size;
    const float* x     = (const float*)d_in[0];
    const int*   ei    = (const int*)d_in[1];
    const int*   batch = (const int*)d_in[2];
    const float* T     = (const float*)d_in[3];
    const float* W1 = (const float*)d_in[4];   const float* b1 = (const float*)d_in[5];
    const float* W2 = (const float*)d_in[6];   const float* b2 = (const float*)d_in[7];
    const float* W3 = (const float*)d_in[8];   const float* b3 = (const float*)d_in[9];
    const float* Wg1 = (const float*)d_in[10]; const float* bg1 = (const float*)d_in[11];
    const float* Wg2 = (const float*)d_in[12]; const float* bg2 = (const float*)d_in[13];
    const float* Kxt = (const float*)d_in[14]; const float* bxt = (const float*)d_in[15];
    const float* Wxt = (const float*)d_in[16]; const float* bxt2 = (const float*)d_in[17];
    const float* Wf1 = (const float*)d_in[18]; const float* bf1 = (const float*)d_in[19];
    const float* Wf2 = (const float*)d_in[20]; const float* bf2 = (const float*)d_in[21];
    const float* Wo = (const float*)d_in[22];  const float* bo = (const float*)d_in[23];
    const int* src = ei;
    const int* dst = ei + N_EDGESC;

    char* ws = (char*)d_ws;
    size_t off = 0;
    auto alloc = [&](size_t bytes) -> void* {
        void* p = ws + off;
        off += (bytes + 255) & ~(size_t)255;
        return p;
    };
    // total ws usage ~135.6 MB (node feature buffers stored bf16)
    int*   deg      = (int*)alloc((size_t)N_NODESC * 4);
    float* dinv     = (float*)alloc((size_t)N_NODESC * 4);
    int*   row_ptr  = (int*)alloc((size_t)(N_NODESC + 1) * 4);
    int*   fillc    = (int*)alloc((size_t)N_NODESC * 4);
    int*   csr_src  = (int*)alloc((size_t)N_EDGESC * 4);
    int*   csums    = (int*)alloc((size_t)4096 * 4);
    int*   bptr     = (int*)alloc((size_t)(NBATCH + 1) * 4);
    float* g0       = (float*)alloc((size_t)NBATCH * 312 * 4);
    float* g1       = (float*)alloc((size_t)NBATCH * 1024 * 4);
    float* convb    = (float*)alloc((size_t)NBATCH * 384 * 4);
    float* xc       = (float*)alloc((size_t)NBATCH * 256 * 4);
    float* f1       = (float*)alloc((size_t)NBATCH * 1024 * 4);
    float* f2       = (float*)alloc((size_t)NBATCH * 512 * 4);
    bf16*  bufA     = (bf16*)alloc((size_t)N_NODESC * 312 * 2); // xw buffers
    bf16*  bufB     = (bf16*)alloc((size_t)N_NODESC * 312 * 2); // h buffers
    float* out      = (float*)d_out;

    const int TPB = 256;

    // ---- graph structure (per call; deterministic work) ----
    zero_ints<<<divup(N_NODESC, TPB), TPB, 0, stream>>>(deg, N_NODESC);
    count_deg<<<divup(N_EDGESC, TPB), TPB, 0, stream>>>(dst, deg, N_EDGESC);
    compute_dinv<<<divup(N_NODESC, TPB), TPB, 0, stream>>>(deg, dinv, N_NODESC);
    int nchunks = divup(N_NODESC, SCAN_CHUNK);
    scan_chunks<<<nchunks, 256, 0, stream>>>(deg, row_ptr, csums, N_NODESC);
    scan_sums<<<1, 64, 0, stream>>>(csums, nchunks);
    finalize_rowptr<<<divup(N_NODESC, TPB), TPB, 0, stream>>>(row_ptr, csums, fillc, N_NODESC, N_EDGESC);
    fill_csr<<<divup(N_EDGESC, TPB), TPB, 0, stream>>>(src, dst, fillc, csr_src, N_EDGESC);
    build_batch_ptr<<<divup(N_NODESC, TPB), TPB, 0, stream>>>(batch, bptr, N_NODESC, NBATCH);

    // ---- GCN layer 1: 78 -> 78 ----
    gemm_tiled<78, 78, false, false><<<dim3(divup(N_NODESC, 64), 2), 256, 0, stream>>>(
        x, W1, (const float*)nullptr, bufA, N_NODESC, 78, 0);
    gcn_gather_relu<78><<<N_NODESC, 128, 0, stream>>>(bufA, row_ptr, csr_src, dinv, b1, bufB);

    // ---- GCN layer 2: 78 -> 156 ----
    gemm_tiled<78, 156, false, false><<<dim3(divup(N_NODESC, 64), 3), 256, 0, stream>>>(
        bufB, W2, (const float*)nullptr, bufA, N_NODESC, 156, 0);
    gcn_gather_relu<156><<<N_NODESC, 192, 0, stream>>>(bufA, row_ptr, csr_src, dinv, b2, bufB);

    // ---- GCN layer 3: 156 -> 312 ----
    gemm_tiled<156, 312, false, false><<<dim3(divup(N_NODESC, 64), 5), 256, 0, stream>>>(
        bufB, W3, (const float*)nullptr, bufA, N_NODESC, 312, 0);
    gcn_gather_relu<312><<<N_NODESC, 320, 0, stream>>>(bufA, row_ptr, csr_src, dinv, b3, bufB);

    // ---- global max pool over batch segments ----
    seg_max<<<NBATCH, 320, 0, stream>>>(bufB, bptr, g0);

    // ---- graph head ----
    gemm_tiled<312, 1024, true, true><<<dim3(divup(NBATCH, 64), 16), 256, 0, stream>>>(
        g0, Wg1, bg1, g1, NBATCH, 1024, 0);
    gemm_tiled<1024, 128, false, true><<<dim3(divup(NBATCH, 64), 2), 256, 0, stream>>>(
        g1, Wg2, bg2, xc, NBATCH, 256, 0);

    // ---- protein branch ----
    conv1d_prot<<<NBATCH, 384, 0, stream>>>(T, Kxt, bxt, convb);
    gemm_tiled<384, 128, false, true><<<dim3(divup(NBATCH, 64), 2), 256, 0, stream>>>(
        convb, Wxt, bxt2, xc, NBATCH, 256, 128);

    // ---- fusion MLP ----
    gemm_tiled<256, 1024, true, true><<<dim3(divup(NBATCH, 64), 16), 256, 0, stream>>>(
        xc, Wf1, bf1, f1, NBATCH, 1024, 0);
    gemm_tiled<1024, 512, true, true><<<dim3(divup(NBATCH, 64), 8), 256, 0, stream>>>(
        f1, Wf2, bf2, f2, NBATCH, 512, 0);
    final_out<<<divup(NBATCH, 4), 256, 0, stream>>>(f2, Wo, bo, out);
}

// Round 6
// 1282.209 us; speedup vs baseline: 1.1843x; 1.1843x over previous
//
#include <hip/hip_runtime.h>
#include <hip/hip_bf16.h>
#include <cstddef>
#include <cstdint>

#define N_NODESC 100000
#define N_EDGESC 500000
#define NBATCH   512
#define SCAN_CHUNK 1024
#define CONV_KSPLIT 4
#define CONV_KCHUNK 1504   // multiple of 32 (and of 8) -> k-octets stay channel-aligned

static inline int divup(int a, int b) { return (a + b - 1) / b; }

typedef __hip_bfloat16 bf16;
typedef short s16x8 __attribute__((ext_vector_type(8)));
typedef float f32x4 __attribute__((ext_vector_type(4)));

__device__ inline float b2f(ushort u) {
    union { ushort s[2]; float f; } c; c.s[0] = 0; c.s[1] = u; return c.f;
}
__device__ inline ushort f2bs(float v) {
    bf16 b = __float2bfloat16(v);
    return *reinterpret_cast<ushort*>(&b);
}

// ---------------- zero ints ----------------
__global__ void zero_ints(int* __restrict__ p, int n) {
    int i = blockIdx.x * blockDim.x + threadIdx.x;
    if (i < n) p[i] = 0;
}

// ---------------- degree / dinv ----------------
__global__ void count_deg(const int* __restrict__ dst, int* __restrict__ deg, int e) {
    int i = blockIdx.x * blockDim.x + threadIdx.x;
    if (i < e) atomicAdd(&deg[dst[i]], 1);
}

__global__ void compute_dinv(const int* __restrict__ deg, float* __restrict__ dinv, int n) {
    int i = blockIdx.x * blockDim.x + threadIdx.x;
    if (i < n) dinv[i] = 1.0f / sqrtf((float)deg[i] + 1.0f);
}

// ---------------- exclusive scan (3-phase) ----------------
__global__ void scan_chunks(const int* __restrict__ deg, int* __restrict__ out,
                            int* __restrict__ sums, int n) {
    __shared__ int sdata[256];
    int t = threadIdx.x;
    int base = blockIdx.x * SCAN_CHUNK;
    int v[4];
    int s = 0;
#pragma unroll
    for (int j = 0; j < 4; ++j) {
        int idx = base + t * 4 + j;
        v[j] = s;
        int d = (idx < n) ? deg[idx] : 0;
        s += d;
    }
    int x = s;
    sdata[t] = x;
    __syncthreads();
    for (int off = 1; off < 256; off <<= 1) {
        int y = (t >= off) ? sdata[t - off] : 0;
        __syncthreads();
        x += y;
        sdata[t] = x;
        __syncthreads();
    }
    int thread_excl = x - s;
    if (t == 255) sums[blockIdx.x] = x;
#pragma unroll
    for (int j = 0; j < 4; ++j) {
        int idx = base + t * 4 + j;
        if (idx < n) out[idx] = thread_excl + v[j];
    }
}

__global__ void scan_sums(int* sums, int nchunks) {
    if (threadIdx.x == 0 && blockIdx.x == 0) {
        int acc = 0;
        for (int i = 0; i < nchunks; ++i) { int v = sums[i]; sums[i] = acc; acc += v; }
    }
}

__global__ void finalize_rowptr(int* __restrict__ row_ptr, const int* __restrict__ sums,
                                int* __restrict__ fill, int n, int e) {
    int i = blockIdx.x * blockDim.x + threadIdx.x;
    if (i < n) {
        int v = row_ptr[i] + sums[i / SCAN_CHUNK];
        row_ptr[i] = v;
        fill[i] = v;
    }
    if (i == 0) row_ptr[n] = e;
}

__global__ void fill_csr(const int* __restrict__ src, const int* __restrict__ dst,
                         int* __restrict__ fill, int* __restrict__ csr_src, int e) {
    int i = blockIdx.x * blockDim.x + threadIdx.x;
    if (i < e) {
        int d = dst[i];
        int pos = atomicAdd(&fill[d], 1);
        csr_src[pos] = src[i];
    }
}

// ---------------- batch segment pointers (batch is sorted) ----------------
__global__ void build_batch_ptr(const int* __restrict__ batch, int* __restrict__ bptr,
                                int n, int nb) {
    int i = blockIdx.x * blockDim.x + threadIdx.x;
    if (i >= n) return;
    int b = batch[i];
    int prev = (i == 0) ? -1 : batch[i - 1];
    for (int bb = prev + 1; bb <= b; ++bb) bptr[bb] = i;
    if (i == n - 1) {
        for (int bb = b + 1; bb <= nb; ++bb) bptr[bb] = n;
    }
}

// ---------------- fp32 -> bf16 node-feature conversion with padded stride ----------------
__global__ void convert_x_bf16(const float* __restrict__ x, ushort* __restrict__ xbf,
                               int n, int ki, int ld) {
    int i = blockIdx.x * blockDim.x + threadIdx.x;
    int total = n * ld;
    if (i >= total) return;
    int node = i / ld, col = i % ld;
    xbf[i] = (col < ki) ? f2bs(x[(size_t)node * ki + col]) : (ushort)0;
}

// ---------------- W[KI,KO] fp32 -> Wt[KO,LD] bf16 (transposed, zero-padded) ----------------
__global__ void transpose_w_bf16(const float* __restrict__ W, ushort* __restrict__ Wt,
                                 int ki, int ko, int ld) {
    int i = blockIdx.x * blockDim.x + threadIdx.x;
    int total = ko * ld;
    if (i >= total) return;
    int o = i / ld, k = i % ld;
    Wt[i] = (k < ki) ? f2bs(W[(size_t)k * ko + o]) : (ushort)0;
}

// ---------------- bf16 MFMA GEMM: C[n,LDC] = A[n,LDA] @ Wt[KO,LDA]^T ----------------
template <int KI, int LDA, int KO, int LDC>
__global__ __launch_bounds__(256) void gemm_mfma(const ushort* __restrict__ A,
                                                 const ushort* __restrict__ Bt,
                                                 ushort* __restrict__ C, int n) {
    __shared__ ushort sA[64][40];
    __shared__ ushort sB[64][40];
    const int t = threadIdx.x;
    const int row0 = blockIdx.x * 64;
    const int col0 = blockIdx.y * 64;
    const int wid = t >> 6, lane = t & 63;
    const int wr = wid >> 1, wc = wid & 1;
    const int lrow = lane & 15;
    const int kgrp = lane >> 4;
    const int srr = t >> 2;      // staging row 0..63
    const int skq = t & 3;       // staging k-octet
    f32x4 acc[2][2];
#pragma unroll
    for (int i = 0; i < 2; ++i)
#pragma unroll
        for (int j = 0; j < 2; ++j) acc[i][j] = (f32x4)0.f;

    const int nk = (KI + 31) / 32;
    for (int ks = 0; ks < nk; ++ks) {
        const int kbase = ks * 32 + skq * 8;
        {   // stage A tile (64 rows x 32 k)
            int grow = row0 + srr;
            uint4 v = {0, 0, 0, 0};
            if (grow < n && kbase < LDA)
                v = *reinterpret_cast<const uint4*>(&A[(size_t)grow * LDA + kbase]);
            *reinterpret_cast<uint4*>(&sA[srr][skq * 8]) = v;
        }
        {   // stage B tile (64 cols x 32 k)
            int gcol = col0 + srr;
            uint4 v = {0, 0, 0, 0};
            if (gcol < KO && kbase < LDA)
                v = *reinterpret_cast<const uint4*>(&Bt[(size_t)gcol * LDA + kbase]);
            *reinterpret_cast<uint4*>(&sB[srr][skq * 8]) = v;
        }
        __syncthreads();
        s16x8 a0 = *reinterpret_cast<const s16x8*>(&sA[wr * 32 + lrow][kgrp * 8]);
        s16x8 a1 = *reinterpret_cast<const s16x8*>(&sA[wr * 32 + 16 + lrow][kgrp * 8]);
        s16x8 b0 = *reinterpret_cast<const s16x8*>(&sB[wc * 32 + lrow][kgrp * 8]);
        s16x8 b1 = *reinterpret_cast<const s16x8*>(&sB[wc * 32 + 16 + lrow][kgrp * 8]);
        acc[0][0] = __builtin_amdgcn_mfma_f32_16x16x32_bf16(a0, b0, acc[0][0], 0, 0, 0);
        acc[0][1] = __builtin_amdgcn_mfma_f32_16x16x32_bf16(a0, b1, acc[0][1], 0, 0, 0);
        acc[1][0] = __builtin_amdgcn_mfma_f32_16x16x32_bf16(a1, b0, acc[1][0], 0, 0, 0);
        acc[1][1] = __builtin_amdgcn_mfma_f32_16x16x32_bf16(a1, b1, acc[1][1], 0, 0, 0);
        __syncthreads();
    }
#pragma unroll
    for (int fr = 0; fr < 2; ++fr)
#pragma unroll
        for (int fc = 0; fc < 2; ++fc)
#pragma unroll
            for (int r = 0; r < 4; ++r) {
                int row = row0 + wr * 32 + fr * 16 + kgrp * 4 + r;
                int col = col0 + wc * 32 + fc * 16 + lrow;
                if (row < n && col < LDC)
                    C[(size_t)row * LDC + col] = (col < KO) ? f2bs(acc[fr][fc][r]) : (ushort)0;
            }
}

// ---------------- GCN aggregation (gather over dst-CSR) + self loop + bias + relu ----------------
template <int F, int LD>
__global__ void gcn_gather_relu(const ushort* __restrict__ xw, const int* __restrict__ row_ptr,
                                const int* __restrict__ csr_src, const float* __restrict__ dinv,
                                const float* __restrict__ b, ushort* __restrict__ hout) {
    int node = blockIdx.x;
    int f = threadIdx.x;
    if (f >= LD) return;
    if (f >= F) { hout[(size_t)node * LD + f] = 0; return; }
    float dn = dinv[node];
    int e0 = row_ptr[node], e1 = row_ptr[node + 1];
    float acc = b2f(xw[(size_t)node * LD + f]) * dn * dn;
    for (int e = e0; e < e1; ++e) {
        int s = csr_src[e];
        acc = fmaf(b2f(xw[(size_t)s * LD + f]), dinv[s] * dn, acc);
    }
    acc += b[f];
    hout[(size_t)node * LD + f] = f2bs(fmaxf(acc, 0.f));
}

// ---------------- segment max pool (batch segments) ----------------
__global__ void seg_max(const ushort* __restrict__ h, const int* __restrict__ bptr,
                        float* __restrict__ g) {
    int b = blockIdx.x;
    int f = threadIdx.x;
    if (f >= 312) return;
    int n0 = bptr[b], n1 = bptr[b + 1];
    float m = -INFINITY;
    for (int n = n0; n < n1; ++n) m = fmaxf(m, b2f(h[(size_t)n * 312 + f]));
    g[(size_t)b * 312 + f] = m;
}

// ---------------- generic fp32 tiled GEMM (head) ----------------
template <int KI, int KO, bool RELU, bool BIAS>
__global__ __launch_bounds__(256) void gemm_tiled(const float* __restrict__ A,
                                                  const float* __restrict__ W,
                                                  const float* __restrict__ bias,
                                                  float* __restrict__ C,
                                                  int n, int ldc, int col_off) {
    __shared__ float sA[16][65];
    __shared__ float sW[16][65];
    const int tid = threadIdx.x;
    const int tr = tid >> 4, tc = tid & 15;
    const int row0 = blockIdx.x * 64;
    const int col0 = blockIdx.y * 64;
    float acc[4][4] = {};
    for (int k0 = 0; k0 < KI; k0 += 16) {
        {
            int r = tid >> 4;
            int kk = tid & 15;
#pragma unroll
            for (int i = 0; i < 4; ++i) {
                int rr = r + 16 * i;
                int grow = row0 + rr;
                float v = 0.f;
                if (grow < n && (k0 + kk) < KI) v = A[(size_t)grow * KI + k0 + kk];
                sA[kk][rr] = v;
            }
        }
        {
            int kk = tid >> 6;
            int c = tid & 63;
#pragma unroll
            for (int i = 0; i < 4; ++i) {
                int kkk = kk + 4 * i;
                float v = 0.f;
                if ((k0 + kkk) < KI && (col0 + c) < KO) v = W[(size_t)(k0 + kkk) * KO + col0 + c];
                sW[kkk][c] = v;
            }
        }
        __syncthreads();
#pragma unroll
        for (int k = 0; k < 16; ++k) {
            float a0 = sA[k][tr], a1 = sA[k][tr + 16], a2 = sA[k][tr + 32], a3 = sA[k][tr + 48];
            float w0 = sW[k][tc], w1 = sW[k][tc + 16], w2 = sW[k][tc + 32], w3 = sW[k][tc + 48];
            acc[0][0] = fmaf(a0, w0, acc[0][0]); acc[0][1] = fmaf(a0, w1, acc[0][1]);
            acc[0][2] = fmaf(a0, w2, acc[0][2]); acc[0][3] = fmaf(a0, w3, acc[0][3]);
            acc[1][0] = fmaf(a1, w0, acc[1][0]); acc[1][1] = fmaf(a1, w1, acc[1][1]);
            acc[1][2] = fmaf(a1, w2, acc[1][2]); acc[1][3] = fmaf(a1, w3, acc[1][3]);
            acc[2][0] = fmaf(a2, w0, acc[2][0]); acc[2][1] = fmaf(a2, w1, acc[2][1]);
            acc[2][2] = fmaf(a2, w2, acc[2][2]); acc[2][3] = fmaf(a2, w3, acc[2][3]);
            acc[3][0] = fmaf(a3, w0, acc[3][0]); acc[3][1] = fmaf(a3, w1, acc[3][1]);
            acc[3][2] = fmaf(a3, w2, acc[3][2]); acc[3][3] = fmaf(a3, w3, acc[3][3]);
        }
        __syncthreads();
    }
#pragma unroll
    for (int i = 0; i < 4; ++i) {
        int grow = row0 + tr + 16 * i;
        if (grow >= n) continue;
#pragma unroll
        for (int j = 0; j < 4; ++j) {
            int gcol = col0 + tc + 16 * j;
            if (gcol >= KO) continue;
            float v = acc[i][j];
            if (BIAS) v += bias[gcol];
            if (RELU) v = fmaxf(v, 0.f);
            C[(size_t)grow * ldc + col_off + gcol] = v;
        }
    }
}

// ---------------- Conv1d as implicit GEMM, K-split ----------------
// C[6144,32] = A[6144,6000] @ B[6000,32]; A[(b*12+h),(i*8+kh)] = T[b,i,h+kh]; B[k,o] = Kxt[o,k].
// K-split boundaries MUST be multiples of 8 (octet = one channel's 8 taps);
// CONV_KCHUNK=1504 is a multiple of 32. Last chunk is ragged (4512..6000), guards handle it.
__global__ __launch_bounds__(256) void conv_gemm(const float* __restrict__ T,
                                                 const float* __restrict__ Kxt,
                                                 float* __restrict__ partial) {
    __shared__ float sA[32][66];
    __shared__ float sW[32][36];
    const int t = threadIdx.x;
    const int row0 = blockIdx.x * 64;
    const int split = blockIdx.y;
    const int kbeg = split * CONV_KCHUNK;
    const int kend = min(6000, kbeg + CONV_KCHUNK);
    const int r0 = (t >> 3) * 2;   // row pair (even)
    const int c0 = (t & 7) * 4;    // col quad
    float acc[2][4] = {};
    for (int k0 = kbeg; k0 < kend; k0 += 32) {
        {   // stage A: thread -> row rr, k-octet kq   (kb is a multiple of 8)
            int rr = t >> 2, kq = t & 3;
            int grow = row0 + rr;                 // < 6144 always
            int b = grow / 12, h = grow % 12;
            int kb = k0 + kq * 8;
            int i = kb >> 3;
            const float* tp = &T[(size_t)b * 14250 + (size_t)i * 19 + h];
#pragma unroll
            for (int j = 0; j < 8; ++j)
                sA[kq * 8 + j][rr] = (kb + j < kend) ? tp[j] : 0.f;
        }
        {   // stage B: thread -> k = t&31, o-quad (t>>5)*4
            int kk = t & 31, ob = (t >> 5) * 4;
            int gk = k0 + kk;
#pragma unroll
            for (int j = 0; j < 4; ++j)
                sW[kk][ob + j] = (gk < kend) ? Kxt[(size_t)(ob + j) * 6000 + gk] : 0.f;
        }
        __syncthreads();
#pragma unroll 8
        for (int k = 0; k < 32; ++k) {
            float2 a = *reinterpret_cast<const float2*>(&sA[k][r0]);
            float4 w = *reinterpret_cast<const float4*>(&sW[k][c0]);
            acc[0][0] = fmaf(a.x, w.x, acc[0][0]); acc[0][1] = fmaf(a.x, w.y, acc[0][1]);
            acc[0][2] = fmaf(a.x, w.z, acc[0][2]); acc[0][3] = fmaf(a.x, w.w, acc[0][3]);
            acc[1][0] = fmaf(a.y, w.x, acc[1][0]); acc[1][1] = fmaf(a.y, w.y, acc[1][1]);
            acc[1][2] = fmaf(a.y, w.z, acc[1][2]); acc[1][3] = fmaf(a.y, w.w, acc[1][3]);
        }
        __syncthreads();
    }
#pragma unroll
    for (int ri = 0; ri < 2; ++ri) {
        int row = row0 + r0 + ri;
        int b = row / 12, h = row % 12;
#pragma unroll
        for (int j = 0; j < 4; ++j)
            partial[(((size_t)split * NBATCH + b) * 32 + (c0 + j)) * 12 + h] = acc[ri][j];
    }
}

__global__ void conv_reduce(const float* __restrict__ partial, const float* __restrict__ bxt,
                            float* __restrict__ convb) {
    int j = blockIdx.x * blockDim.x + threadIdx.x;
    if (j >= NBATCH * 384) return;
    int b = j / 384, rem = j % 384;
    int o = rem / 12, h = rem % 12;
    float acc = bxt[o];
#pragma unroll
    for (int s = 0; s < CONV_KSPLIT; ++s)
        acc += partial[(((size_t)s * NBATCH + b) * 32 + o) * 12 + h];
    convb[j] = acc;
}

// ---------------- final [512,512] @ [512,1] ----------------
__global__ void final_out(const float* __restrict__ f2, const float* __restrict__ Wo,
                          const float* __restrict__ bo, float* __restrict__ out) {
    int row = blockIdx.x * (blockDim.x / 64) + (threadIdx.x / 64);
    int lane = threadIdx.x & 63;
    if (row >= NBATCH) return;
    float acc = 0.f;
    for (int k = lane; k < 512; k += 64) acc = fmaf(f2[(size_t)row * 512 + k], Wo[k], acc);
#pragma unroll
    for (int off = 32; off > 0; off >>= 1) acc += __shfl_down(acc, off);
    if (lane == 0) out[row] = acc + bo[0];
}

extern "C" void kernel_launch(void* const* d_in, const int* in_sizes, int n_in,
                              void* d_out, int out_size, void* d_ws, size_t ws_size,
                              hipStream_t stream) {
    (void)in_sizes; (void)n_in; (void)out_size; (void)ws_size;
    const float* x     = (const float*)d_in[0];
    const int*   ei    = (const int*)d_in[1];
    const int*   batch = (const int*)d_in[2];
    const float* T     = (const float*)d_in[3];
    const float* W1 = (const float*)d_in[4];   const float* b1 = (const float*)d_in[5];
    const float* W2 = (const float*)d_in[6];   const float* b2 = (const float*)d_in[7];
    const float* W3 = (const float*)d_in[8];   const float* b3 = (const float*)d_in[9];
    const float* Wg1 = (const float*)d_in[10]; const float* bg1 = (const float*)d_in[11];
    const float* Wg2 = (const float*)d_in[12]; const float* bg2 = (const float*)d_in[13];
    const float* Kxt = (const float*)d_in[14]; const float* bxt = (const float*)d_in[15];
    const float* Wxt = (const float*)d_in[16]; const float* bxt2 = (const float*)d_in[17];
    const float* Wf1 = (const float*)d_in[18]; const float* bf1 = (const float*)d_in[19];
    const float* Wf2 = (const float*)d_in[20]; const float* bf2 = (const float*)d_in[21];
    const float* Wo = (const float*)d_in[22];  const float* bo = (const float*)d_in[23];
    const int* src = ei;
    const int* dst = ei + N_EDGESC;

    char* ws = (char*)d_ws;
    size_t off = 0;
    auto alloc = [&](size_t bytes) -> void* {
        void* p = ws + off;
        off += (bytes + 255) & ~(size_t)255;
        return p;
    };
    // ~155 MB total
    int*   deg      = (int*)alloc((size_t)N_NODESC * 4);
    float* dinv     = (float*)alloc((size_t)N_NODESC * 4);
    int*   row_ptr  = (int*)alloc((size_t)(N_NODESC + 1) * 4);
    int*   fillc    = (int*)alloc((size_t)N_NODESC * 4);
    int*   csr_src  = (int*)alloc((size_t)N_EDGESC * 4);
    int*   csums    = (int*)alloc((size_t)4096 * 4);
    int*   bptr     = (int*)alloc((size_t)(NBATCH + 1) * 4);
    float* g0       = (float*)alloc((size_t)NBATCH * 312 * 4);
    float* g1       = (float*)alloc((size_t)NBATCH * 1024 * 4);
    float* convb    = (float*)alloc((size_t)NBATCH * 384 * 4);
    float* xc       = (float*)alloc((size_t)NBATCH * 256 * 4);
    float* f1       = (float*)alloc((size_t)NBATCH * 1024 * 4);
    float* f2       = (float*)alloc((size_t)NBATCH * 512 * 4);
    float* cpart    = (float*)alloc((size_t)CONV_KSPLIT * NBATCH * 32 * 12 * 4);
    ushort* xbf     = (ushort*)alloc((size_t)N_NODESC * 80 * 2);
    ushort* Wt1     = (ushort*)alloc((size_t)78 * 80 * 2);
    ushort* Wt2     = (ushort*)alloc((size_t)156 * 80 * 2);
    ushort* Wt3     = (ushort*)alloc((size_t)312 * 160 * 2);
    ushort* bufA    = (ushort*)alloc((size_t)N_NODESC * 312 * 2);
    ushort* bufB    = (ushort*)alloc((size_t)N_NODESC * 312 * 2);
    float* out      = (float*)d_out;

    const int TPB = 256;

    // ---- graph structure ----
    zero_ints<<<divup(N_NODESC, TPB), TPB, 0, stream>>>(deg, N_NODESC);
    count_deg<<<divup(N_EDGESC, TPB), TPB, 0, stream>>>(dst, deg, N_EDGESC);
    compute_dinv<<<divup(N_NODESC, TPB), TPB, 0, stream>>>(deg, dinv, N_NODESC);
    int nchunks = divup(N_NODESC, SCAN_CHUNK);
    scan_chunks<<<nchunks, 256, 0, stream>>>(deg, row_ptr, csums, N_NODESC);
    scan_sums<<<1, 64, 0, stream>>>(csums, nchunks);
    finalize_rowptr<<<divup(N_NODESC, TPB), TPB, 0, stream>>>(row_ptr, csums, fillc, N_NODESC, N_EDGESC);
    fill_csr<<<divup(N_EDGESC, TPB), TPB, 0, stream>>>(src, dst, fillc, csr_src, N_EDGESC);
    build_batch_ptr<<<divup(N_NODESC, TPB), TPB, 0, stream>>>(batch, bptr, N_NODESC, NBATCH);

    // ---- bf16 conversions ----
    convert_x_bf16<<<divup(N_NODESC * 80, TPB), TPB, 0, stream>>>(x, xbf, N_NODESC, 78, 80);
    transpose_w_bf16<<<divup(78 * 80, TPB), TPB, 0, stream>>>(W1, Wt1, 78, 78, 80);
    transpose_w_bf16<<<divup(156 * 80, TPB), TPB, 0, stream>>>(W2, Wt2, 78, 156, 80);
    transpose_w_bf16<<<divup(312 * 160, TPB), TPB, 0, stream>>>(W3, Wt3, 156, 312, 160);

    // ---- GCN layer 1: 78 -> 78 (LD 80) ----
    gemm_mfma<78, 80, 78, 80><<<dim3(divup(N_NODESC, 64), 2), 256, 0, stream>>>(xbf, Wt1, bufA, N_NODESC);
    gcn_gather_relu<78, 80><<<N_NODESC, 128, 0, stream>>>(bufA, row_ptr, csr_src, dinv, b1, bufB);

    // ---- GCN layer 2: 78 -> 156 (LD 160) ----
    gemm_mfma<78, 80, 156, 160><<<dim3(divup(N_NODESC, 64), 3), 256, 0, stream>>>(bufB, Wt2, bufA, N_NODESC);
    gcn_gather_relu<156, 160><<<N_NODESC, 192, 0, stream>>>(bufA, row_ptr, csr_src, dinv, b2, bufB);

    // ---- GCN layer 3: 156 -> 312 ----
    gemm_mfma<156, 160, 312, 312><<<dim3(divup(N_NODESC, 64), 5), 256, 0, stream>>>(bufB, Wt3, bufA, N_NODESC);
    gcn_gather_relu<312, 312><<<N_NODESC, 320, 0, stream>>>(bufA, row_ptr, csr_src, dinv, b3, bufB);

    // ---- global max pool ----
    seg_max<<<NBATCH, 320, 0, stream>>>(bufB, bptr, g0);

    // ---- graph head (fp32) ----
    gemm_tiled<312, 1024, true, true><<<dim3(divup(NBATCH, 64), 16), 256, 0, stream>>>(
        g0, Wg1, bg1, g1, NBATCH, 1024, 0);
    gemm_tiled<1024, 128, false, true><<<dim3(divup(NBATCH, 64), 2), 256, 0, stream>>>(
        g1, Wg2, bg2, xc, NBATCH, 256, 0);

    // ---- protein branch: implicit-GEMM conv ----
    conv_gemm<<<dim3(6144 / 64, CONV_KSPLIT), 256, 0, stream>>>(T, Kxt, cpart);
    conv_reduce<<<divup(NBATCH * 384, TPB), TPB, 0, stream>>>(cpart, bxt, convb);
    gemm_tiled<384, 128, false, true><<<dim3(divup(NBATCH, 64), 2), 256, 0, stream>>>(
        convb, Wxt, bxt2, xc, NBATCH, 256, 128);

    // ---- fusion MLP ----
    gemm_tiled<256, 1024, true, true><<<dim3(divup(NBATCH, 64), 16), 256, 0, stream>>>(
        xc, Wf1, bf1, f1, NBATCH, 1024, 0);
    gemm_tiled<1024, 512, true, true><<<dim3(divup(NBATCH, 64), 8), 256, 0, stream>>>(
        f1, Wf2, bf2, f2, NBATCH, 512, 0);
    final_out<<<divup(NBATCH, 4), 256, 0, stream>>>(f2, Wo, bo, out);
}

// Round 7
// 998.645 us; speedup vs baseline: 1.5206x; 1.2839x over previous
//
#include <hip/hip_runtime.h>
#include <hip/hip_bf16.h>
#include <cstddef>
#include <cstdint>

#define N_NODESC 100000
#define N_EDGESC 500000
#define NBATCH   512
#define SCAN_CHUNK 1024
#define CONV_KSPLIT 4
#define CONV_KCHUNK 1504   // multiple of 32 -> k-octets stay channel-aligned

static inline int divup(int a, int b) { return (a + b - 1) / b; }

typedef __hip_bfloat16 bf16;
typedef short s16x8 __attribute__((ext_vector_type(8)));
typedef float f32x4 __attribute__((ext_vector_type(4)));

__device__ inline float b2f(ushort u) {
    union { uint i; float f; } c; c.i = (uint)u << 16; return c.f;
}
__device__ inline ushort f2bs(float v) {
    bf16 b = __float2bfloat16(v);
    return *reinterpret_cast<ushort*>(&b);
}
__device__ inline void unpack2(uint u, float& a, float& b) {
    union { uint i; float f; } lo, hi;
    lo.i = u << 16; hi.i = u & 0xffff0000u;
    a = lo.f; b = hi.f;
}

// ---------------- zero ints ----------------
__global__ void zero_ints(int* __restrict__ p, int n) {
    int i = blockIdx.x * blockDim.x + threadIdx.x;
    if (i < n) p[i] = 0;
}

// ---------------- degree / dinv ----------------
__global__ void count_deg(const int* __restrict__ dst, int* __restrict__ deg, int e) {
    int i = blockIdx.x * blockDim.x + threadIdx.x;
    if (i < e) atomicAdd(&deg[dst[i]], 1);
}

__global__ void compute_dinv(const int* __restrict__ deg, float* __restrict__ dinv, int n) {
    int i = blockIdx.x * blockDim.x + threadIdx.x;
    if (i < n) dinv[i] = 1.0f / sqrtf((float)deg[i] + 1.0f);
}

// ---------------- exclusive scan (3-phase) ----------------
__global__ void scan_chunks(const int* __restrict__ deg, int* __restrict__ out,
                            int* __restrict__ sums, int n) {
    __shared__ int sdata[256];
    int t = threadIdx.x;
    int base = blockIdx.x * SCAN_CHUNK;
    int v[4];
    int s = 0;
#pragma unroll
    for (int j = 0; j < 4; ++j) {
        int idx = base + t * 4 + j;
        v[j] = s;
        int d = (idx < n) ? deg[idx] : 0;
        s += d;
    }
    int x = s;
    sdata[t] = x;
    __syncthreads();
    for (int off = 1; off < 256; off <<= 1) {
        int y = (t >= off) ? sdata[t - off] : 0;
        __syncthreads();
        x += y;
        sdata[t] = x;
        __syncthreads();
    }
    int thread_excl = x - s;
    if (t == 255) sums[blockIdx.x] = x;
#pragma unroll
    for (int j = 0; j < 4; ++j) {
        int idx = base + t * 4 + j;
        if (idx < n) out[idx] = thread_excl + v[j];
    }
}

__global__ void scan_sums(int* sums, int nchunks) {
    if (threadIdx.x == 0 && blockIdx.x == 0) {
        int acc = 0;
        for (int i = 0; i < nchunks; ++i) { int v = sums[i]; sums[i] = acc; acc += v; }
    }
}

__global__ void finalize_rowptr(int* __restrict__ row_ptr, const int* __restrict__ sums,
                                int* __restrict__ fill, int n, int e) {
    int i = blockIdx.x * blockDim.x + threadIdx.x;
    if (i < n) {
        int v = row_ptr[i] + sums[i / SCAN_CHUNK];
        row_ptr[i] = v;
        fill[i] = v;
    }
    if (i == 0) row_ptr[n] = e;
}

__global__ void fill_csr(const int* __restrict__ src, const int* __restrict__ dst,
                         int* __restrict__ fill, int* __restrict__ csr_src, int e) {
    int i = blockIdx.x * blockDim.x + threadIdx.x;
    if (i < e) {
        int d = dst[i];
        int pos = atomicAdd(&fill[d], 1);
        csr_src[pos] = src[i];
    }
}

// ---------------- batch segment pointers (batch is sorted) ----------------
__global__ void build_batch_ptr(const int* __restrict__ batch, int* __restrict__ bptr,
                                int n, int nb) {
    int i = blockIdx.x * blockDim.x + threadIdx.x;
    if (i >= n) return;
    int b = batch[i];
    int prev = (i == 0) ? -1 : batch[i - 1];
    for (int bb = prev + 1; bb <= b; ++bb) bptr[bb] = i;
    if (i == n - 1) {
        for (int bb = b + 1; bb <= nb; ++bb) bptr[bb] = n;
    }
}

// ---------------- fp32 -> bf16 node-feature conversion with padded stride ----------------
__global__ void convert_x_bf16(const float* __restrict__ x, ushort* __restrict__ xbf,
                               int n, int ki, int ld) {
    int i = blockIdx.x * blockDim.x + threadIdx.x;
    int total = n * ld;
    if (i >= total) return;
    int node = i / ld, col = i % ld;
    xbf[i] = (col < ki) ? f2bs(x[(size_t)node * ki + col]) : (ushort)0;
}

// ---------------- W[KI,KO] fp32 -> Wt[KO,LD] bf16 (transposed, zero-padded) ----------------
__global__ void transpose_w_bf16(const float* __restrict__ W, ushort* __restrict__ Wt,
                                 int ki, int ko, int ld) {
    int i = blockIdx.x * blockDim.x + threadIdx.x;
    int total = ko * ld;
    if (i >= total) return;
    int o = i / ld, k = i % ld;
    Wt[i] = (k < ki) ? f2bs(W[(size_t)k * ko + o]) : (ushort)0;
}

// ---------------- vectorized GCN aggregation: agg = \hat{A} h  (pure, no bias/relu) ----------------
// thread = (node, 8-feature octet). 16B loads/stores. Pads stay zero (inputs padded w/ zeros).
template <int LD>
__global__ void gcn_gather_vec(const ushort* __restrict__ h, const int* __restrict__ row_ptr,
                               const int* __restrict__ csr_src, const float* __restrict__ dinv,
                               ushort* __restrict__ agg, int n) {
    constexpr int TPN = LD / 8;
    int gid = blockIdx.x * blockDim.x + threadIdx.x;
    int node = gid / TPN, oct = gid % TPN;
    if (node >= n) return;
    float dn = dinv[node];
    int e0 = row_ptr[node], e1 = row_ptr[node + 1];
    float acc[8];
    {   // self loop: dinv^2 * h[node]
        uint4 v = *reinterpret_cast<const uint4*>(&h[(size_t)node * LD + oct * 8]);
        float w = dn * dn;
        float a, b;
        unpack2(v.x, a, b); acc[0] = a * w; acc[1] = b * w;
        unpack2(v.y, a, b); acc[2] = a * w; acc[3] = b * w;
        unpack2(v.z, a, b); acc[4] = a * w; acc[5] = b * w;
        unpack2(v.w, a, b); acc[6] = a * w; acc[7] = b * w;
    }
    for (int e = e0; e < e1; ++e) {
        int s = csr_src[e];
        float w = dinv[s] * dn;
        uint4 v = *reinterpret_cast<const uint4*>(&h[(size_t)s * LD + oct * 8]);
        float a, b;
        unpack2(v.x, a, b); acc[0] = fmaf(a, w, acc[0]); acc[1] = fmaf(b, w, acc[1]);
        unpack2(v.y, a, b); acc[2] = fmaf(a, w, acc[2]); acc[3] = fmaf(b, w, acc[3]);
        unpack2(v.z, a, b); acc[4] = fmaf(a, w, acc[4]); acc[5] = fmaf(b, w, acc[5]);
        unpack2(v.w, a, b); acc[6] = fmaf(a, w, acc[6]); acc[7] = fmaf(b, w, acc[7]);
    }
    uint4 o;
    o.x = (uint)f2bs(acc[0]) | ((uint)f2bs(acc[1]) << 16);
    o.y = (uint)f2bs(acc[2]) | ((uint)f2bs(acc[3]) << 16);
    o.z = (uint)f2bs(acc[4]) | ((uint)f2bs(acc[5]) << 16);
    o.w = (uint)f2bs(acc[6]) | ((uint)f2bs(acc[7]) << 16);
    *reinterpret_cast<uint4*>(&agg[(size_t)node * LD + oct * 8]) = o;
}

// ---------------- bf16 MFMA GEMM: C = A @ Wt^T (+bias)(+relu), bf16 out ----------------
template <int KI, int LDA, int KO, int LDC, bool BIASRELU>
__global__ __launch_bounds__(256) void gemm_mfma(const ushort* __restrict__ A,
                                                 const ushort* __restrict__ Bt,
                                                 const float* __restrict__ bias,
                                                 ushort* __restrict__ C, int n) {
    __shared__ ushort sA[64][40];
    __shared__ ushort sB[64][40];
    const int t = threadIdx.x;
    const int row0 = blockIdx.x * 64;
    const int col0 = blockIdx.y * 64;
    const int wid = t >> 6, lane = t & 63;
    const int wr = wid >> 1, wc = wid & 1;
    const int lrow = lane & 15;
    const int kgrp = lane >> 4;
    const int srr = t >> 2;      // staging row 0..63
    const int skq = t & 3;       // staging k-octet
    f32x4 acc[2][2];
#pragma unroll
    for (int i = 0; i < 2; ++i)
#pragma unroll
        for (int j = 0; j < 2; ++j) acc[i][j] = (f32x4)0.f;

    const int nk = (KI + 31) / 32;
    for (int ks = 0; ks < nk; ++ks) {
        const int kbase = ks * 32 + skq * 8;
        {   // stage A tile (64 rows x 32 k)
            int grow = row0 + srr;
            uint4 v = {0, 0, 0, 0};
            if (grow < n && kbase < LDA)
                v = *reinterpret_cast<const uint4*>(&A[(size_t)grow * LDA + kbase]);
            *reinterpret_cast<uint4*>(&sA[srr][skq * 8]) = v;
        }
        {   // stage B tile (64 cols x 32 k)
            int gcol = col0 + srr;
            uint4 v = {0, 0, 0, 0};
            if (gcol < KO && kbase < LDA)
                v = *reinterpret_cast<const uint4*>(&Bt[(size_t)gcol * LDA + kbase]);
            *reinterpret_cast<uint4*>(&sB[srr][skq * 8]) = v;
        }
        __syncthreads();
        s16x8 a0 = *reinterpret_cast<const s16x8*>(&sA[wr * 32 + lrow][kgrp * 8]);
        s16x8 a1 = *reinterpret_cast<const s16x8*>(&sA[wr * 32 + 16 + lrow][kgrp * 8]);
        s16x8 b0 = *reinterpret_cast<const s16x8*>(&sB[wc * 32 + lrow][kgrp * 8]);
        s16x8 b1 = *reinterpret_cast<const s16x8*>(&sB[wc * 32 + 16 + lrow][kgrp * 8]);
        acc[0][0] = __builtin_amdgcn_mfma_f32_16x16x32_bf16(a0, b0, acc[0][0], 0, 0, 0);
        acc[0][1] = __builtin_amdgcn_mfma_f32_16x16x32_bf16(a0, b1, acc[0][1], 0, 0, 0);
        acc[1][0] = __builtin_amdgcn_mfma_f32_16x16x32_bf16(a1, b0, acc[1][0], 0, 0, 0);
        acc[1][1] = __builtin_amdgcn_mfma_f32_16x16x32_bf16(a1, b1, acc[1][1], 0, 0, 0);
        __syncthreads();
    }
#pragma unroll
    for (int fr = 0; fr < 2; ++fr)
#pragma unroll
        for (int fc = 0; fc < 2; ++fc)
#pragma unroll
            for (int r = 0; r < 4; ++r) {
                int row = row0 + wr * 32 + fr * 16 + kgrp * 4 + r;
                int col = col0 + wc * 32 + fc * 16 + lrow;
                if (row < n && col < LDC) {
                    float v = acc[fr][fc][r];
                    ushort o = 0;
                    if (col < KO) {
                        if (BIASRELU) v = fmaxf(v + bias[col], 0.f);
                        o = f2bs(v);
                    }
                    C[(size_t)row * LDC + col] = o;
                }
            }
}

// ---------------- segment max pool (batch segments) ----------------
__global__ void seg_max(const ushort* __restrict__ h, const int* __restrict__ bptr,
                        float* __restrict__ g) {
    int b = blockIdx.x;
    int f = threadIdx.x;
    if (f >= 312) return;
    int n0 = bptr[b], n1 = bptr[b + 1];
    float m = -INFINITY;
    for (int n = n0; n < n1; ++n) m = fmaxf(m, b2f(h[(size_t)n * 312 + f]));
    g[(size_t)b * 312 + f] = m;
}

// ---------------- generic fp32 tiled GEMM (head) ----------------
template <int KI, int KO, bool RELU, bool BIAS>
__global__ __launch_bounds__(256) void gemm_tiled(const float* __restrict__ A,
                                                  const float* __restrict__ W,
                                                  const float* __restrict__ bias,
                                                  float* __restrict__ C,
                                                  int n, int ldc, int col_off) {
    __shared__ float sA[16][65];
    __shared__ float sW[16][65];
    const int tid = threadIdx.x;
    const int tr = tid >> 4, tc = tid & 15;
    const int row0 = blockIdx.x * 64;
    const int col0 = blockIdx.y * 64;
    float acc[4][4] = {};
    for (int k0 = 0; k0 < KI; k0 += 16) {
        {
            int r = tid >> 4;
            int kk = tid & 15;
#pragma unroll
            for (int i = 0; i < 4; ++i) {
                int rr = r + 16 * i;
                int grow = row0 + rr;
                float v = 0.f;
                if (grow < n && (k0 + kk) < KI) v = A[(size_t)grow * KI + k0 + kk];
                sA[kk][rr] = v;
            }
        }
        {
            int kk = tid >> 6;
            int c = tid & 63;
#pragma unroll
            for (int i = 0; i < 4; ++i) {
                int kkk = kk + 4 * i;
                float v = 0.f;
                if ((k0 + kkk) < KI && (col0 + c) < KO) v = W[(size_t)(k0 + kkk) * KO + col0 + c];
                sW[kkk][c] = v;
            }
        }
        __syncthreads();
#pragma unroll
        for (int k = 0; k < 16; ++k) {
            float a0 = sA[k][tr], a1 = sA[k][tr + 16], a2 = sA[k][tr + 32], a3 = sA[k][tr + 48];
            float w0 = sW[k][tc], w1 = sW[k][tc + 16], w2 = sW[k][tc + 32], w3 = sW[k][tc + 48];
            acc[0][0] = fmaf(a0, w0, acc[0][0]); acc[0][1] = fmaf(a0, w1, acc[0][1]);
            acc[0][2] = fmaf(a0, w2, acc[0][2]); acc[0][3] = fmaf(a0, w3, acc[0][3]);
            acc[1][0] = fmaf(a1, w0, acc[1][0]); acc[1][1] = fmaf(a1, w1, acc[1][1]);
            acc[1][2] = fmaf(a1, w2, acc[1][2]); acc[1][3] = fmaf(a1, w3, acc[1][3]);
            acc[2][0] = fmaf(a2, w0, acc[2][0]); acc[2][1] = fmaf(a2, w1, acc[2][1]);
            acc[2][2] = fmaf(a2, w2, acc[2][2]); acc[2][3] = fmaf(a2, w3, acc[2][3]);
            acc[3][0] = fmaf(a3, w0, acc[3][0]); acc[3][1] = fmaf(a3, w1, acc[3][1]);
            acc[3][2] = fmaf(a3, w2, acc[3][2]); acc[3][3] = fmaf(a3, w3, acc[3][3]);
        }
        __syncthreads();
    }
#pragma unroll
    for (int i = 0; i < 4; ++i) {
        int grow = row0 + tr + 16 * i;
        if (grow >= n) continue;
#pragma unroll
        for (int j = 0; j < 4; ++j) {
            int gcol = col0 + tc + 16 * j;
            if (gcol >= KO) continue;
            float v = acc[i][j];
            if (BIAS) v += bias[gcol];
            if (RELU) v = fmaxf(v, 0.f);
            C[(size_t)grow * ldc + col_off + gcol] = v;
        }
    }
}

// ---------------- Conv1d as implicit GEMM, K-split ----------------
__global__ __launch_bounds__(256) void conv_gemm(const float* __restrict__ T,
                                                 const float* __restrict__ Kxt,
                                                 float* __restrict__ partial) {
    __shared__ float sA[32][66];
    __shared__ float sW[32][36];
    const int t = threadIdx.x;
    const int row0 = blockIdx.x * 64;
    const int split = blockIdx.y;
    const int kbeg = split * CONV_KCHUNK;
    const int kend = min(6000, kbeg + CONV_KCHUNK);
    const int r0 = (t >> 3) * 2;   // row pair (even)
    const int c0 = (t & 7) * 4;    // col quad
    float acc[2][4] = {};
    for (int k0 = kbeg; k0 < kend; k0 += 32) {
        {   // stage A: thread -> row rr, k-octet kq   (kb is a multiple of 8)
            int rr = t >> 2, kq = t & 3;
            int grow = row0 + rr;                 // < 6144 always
            int b = grow / 12, h = grow % 12;
            int kb = k0 + kq * 8;
            int i = kb >> 3;
            const float* tp = &T[(size_t)b * 14250 + (size_t)i * 19 + h];
#pragma unroll
            for (int j = 0; j < 8; ++j)
                sA[kq * 8 + j][rr] = (kb + j < kend) ? tp[j] : 0.f;
        }
        {   // stage B: thread -> k = t&31, o-quad (t>>5)*4
            int kk = t & 31, ob = (t >> 5) * 4;
            int gk = k0 + kk;
#pragma unroll
            for (int j = 0; j < 4; ++j)
                sW[kk][ob + j] = (gk < kend) ? Kxt[(size_t)(ob + j) * 6000 + gk] : 0.f;
        }
        __syncthreads();
#pragma unroll 8
        for (int k = 0; k < 32; ++k) {
            float2 a = *reinterpret_cast<const float2*>(&sA[k][r0]);
            float4 w = *reinterpret_cast<const float4*>(&sW[k][c0]);
            acc[0][0] = fmaf(a.x, w.x, acc[0][0]); acc[0][1] = fmaf(a.x, w.y, acc[0][1]);
            acc[0][2] = fmaf(a.x, w.z, acc[0][2]); acc[0][3] = fmaf(a.x, w.w, acc[0][3]);
            acc[1][0] = fmaf(a.y, w.x, acc[1][0]); acc[1][1] = fmaf(a.y, w.y, acc[1][1]);
            acc[1][2] = fmaf(a.y, w.z, acc[1][2]); acc[1][3] = fmaf(a.y, w.w, acc[1][3]);
        }
        __syncthreads();
    }
#pragma unroll
    for (int ri = 0; ri < 2; ++ri) {
        int row = row0 + r0 + ri;
        int b = row / 12, h = row % 12;
#pragma unroll
        for (int j = 0; j < 4; ++j)
            partial[(((size_t)split * NBATCH + b) * 32 + (c0 + j)) * 12 + h] = acc[ri][j];
    }
}

__global__ void conv_reduce(const float* __restrict__ partial, const float* __restrict__ bxt,
                            float* __restrict__ convb) {
    int j = blockIdx.x * blockDim.x + threadIdx.x;
    if (j >= NBATCH * 384) return;
    int b = j / 384, rem = j % 384;
    int o = rem / 12, h = rem % 12;
    float acc = bxt[o];
#pragma unroll
    for (int s = 0; s < CONV_KSPLIT; ++s)
        acc += partial[(((size_t)s * NBATCH + b) * 32 + o) * 12 + h];
    convb[j] = acc;
}

// ---------------- final [512,512] @ [512,1] ----------------
__global__ void final_out(const float* __restrict__ f2, const float* __restrict__ Wo,
                          const float* __restrict__ bo, float* __restrict__ out) {
    int row = blockIdx.x * (blockDim.x / 64) + (threadIdx.x / 64);
    int lane = threadIdx.x & 63;
    if (row >= NBATCH) return;
    float acc = 0.f;
    for (int k = lane; k < 512; k += 64) acc = fmaf(f2[(size_t)row * 512 + k], Wo[k], acc);
#pragma unroll
    for (int off = 32; off > 0; off >>= 1) acc += __shfl_down(acc, off);
    if (lane == 0) out[row] = acc + bo[0];
}

extern "C" void kernel_launch(void* const* d_in, const int* in_sizes, int n_in,
                              void* d_out, int out_size, void* d_ws, size_t ws_size,
                              hipStream_t stream) {
    (void)in_sizes; (void)n_in; (void)out_size; (void)ws_size;
    const float* x     = (const float*)d_in[0];
    const int*   ei    = (const int*)d_in[1];
    const int*   batch = (const int*)d_in[2];
    const float* T     = (const float*)d_in[3];
    const float* W1 = (const float*)d_in[4];   const float* b1 = (const float*)d_in[5];
    const float* W2 = (const float*)d_in[6];   const float* b2 = (const float*)d_in[7];
    const float* W3 = (const float*)d_in[8];   const float* b3 = (const float*)d_in[9];
    const float* Wg1 = (const float*)d_in[10]; const float* bg1 = (const float*)d_in[11];
    const float* Wg2 = (const float*)d_in[12]; const float* bg2 = (const float*)d_in[13];
    const float* Kxt = (const float*)d_in[14]; const float* bxt = (const float*)d_in[15];
    const float* Wxt = (const float*)d_in[16]; const float* bxt2 = (const float*)d_in[17];
    const float* Wf1 = (const float*)d_in[18]; const float* bf1 = (const float*)d_in[19];
    const float* Wf2 = (const float*)d_in[20]; const float* bf2 = (const float*)d_in[21];
    const float* Wo = (const float*)d_in[22];  const float* bo = (const float*)d_in[23];
    const int* src = ei;
    const int* dst = ei + N_EDGESC;

    char* ws = (char*)d_ws;
    size_t off = 0;
    auto alloc = [&](size_t bytes) -> void* {
        void* p = ws + off;
        off += (bytes + 255) & ~(size_t)255;
        return p;
    };
    // ~125 MB total
    int*   deg      = (int*)alloc((size_t)N_NODESC * 4);
    float* dinv     = (float*)alloc((size_t)N_NODESC * 4);
    int*   row_ptr  = (int*)alloc((size_t)(N_NODESC + 1) * 4);
    int*   fillc    = (int*)alloc((size_t)N_NODESC * 4);
    int*   csr_src  = (int*)alloc((size_t)N_EDGESC * 4);
    int*   csums    = (int*)alloc((size_t)4096 * 4);
    int*   bptr     = (int*)alloc((size_t)(NBATCH + 1) * 4);
    float* g0       = (float*)alloc((size_t)NBATCH * 312 * 4);
    float* g1       = (float*)alloc((size_t)NBATCH * 1024 * 4);
    float* convb    = (float*)alloc((size_t)NBATCH * 384 * 4);
    float* xc       = (float*)alloc((size_t)NBATCH * 256 * 4);
    float* f1       = (float*)alloc((size_t)NBATCH * 1024 * 4);
    float* f2       = (float*)alloc((size_t)NBATCH * 512 * 4);
    float* cpart    = (float*)alloc((size_t)CONV_KSPLIT * NBATCH * 32 * 12 * 4);
    ushort* xbf     = (ushort*)alloc((size_t)N_NODESC * 80 * 2);   // x (80) -> later h1 (80)
    ushort* aggbuf  = (ushort*)alloc((size_t)N_NODESC * 160 * 2);  // agg1/2 (80), agg3 (160)
    ushort* hbuf    = (ushort*)alloc((size_t)N_NODESC * 312 * 2);  // h2 (160), h3 (312)
    ushort* Wt1     = (ushort*)alloc((size_t)78 * 80 * 2);
    ushort* Wt2     = (ushort*)alloc((size_t)156 * 80 * 2);
    ushort* Wt3     = (ushort*)alloc((size_t)312 * 160 * 2);
    float* out      = (float*)d_out;

    const int TPB = 256;

    // ---- graph structure ----
    zero_ints<<<divup(N_NODESC, TPB), TPB, 0, stream>>>(deg, N_NODESC);
    count_deg<<<divup(N_EDGESC, TPB), TPB, 0, stream>>>(dst, deg, N_EDGESC);
    compute_dinv<<<divup(N_NODESC, TPB), TPB, 0, stream>>>(deg, dinv, N_NODESC);
    int nchunks = divup(N_NODESC, SCAN_CHUNK);
    scan_chunks<<<nchunks, 256, 0, stream>>>(deg, row_ptr, csums, N_NODESC);
    scan_sums<<<1, 64, 0, stream>>>(csums, nchunks);
    finalize_rowptr<<<divup(N_NODESC, TPB), TPB, 0, stream>>>(row_ptr, csums, fillc, N_NODESC, N_EDGESC);
    fill_csr<<<divup(N_EDGESC, TPB), TPB, 0, stream>>>(src, dst, fillc, csr_src, N_EDGESC);
    build_batch_ptr<<<divup(N_NODESC, TPB), TPB, 0, stream>>>(batch, bptr, N_NODESC, NBATCH);

    // ---- bf16 conversions ----
    convert_x_bf16<<<divup(N_NODESC * 80, TPB), TPB, 0, stream>>>(x, xbf, N_NODESC, 78, 80);
    transpose_w_bf16<<<divup(78 * 80, TPB), TPB, 0, stream>>>(W1, Wt1, 78, 78, 80);
    transpose_w_bf16<<<divup(156 * 80, TPB), TPB, 0, stream>>>(W2, Wt2, 78, 156, 80);
    transpose_w_bf16<<<divup(312 * 160, TPB), TPB, 0, stream>>>(W3, Wt3, 156, 312, 160);

    // ---- GCN layer 1: agg(x) -> gemm+bias+relu -> h1 (LD 80) ----
    gcn_gather_vec<80><<<divup(N_NODESC * 10, TPB), TPB, 0, stream>>>(
        xbf, row_ptr, csr_src, dinv, aggbuf, N_NODESC);
    gemm_mfma<78, 80, 78, 80, true><<<dim3(divup(N_NODESC, 64), 2), 256, 0, stream>>>(
        aggbuf, Wt1, b1, xbf, N_NODESC);   // h1 overwrites xbf (x dead)

    // ---- GCN layer 2: agg(h1) -> gemm -> h2 (LD 160) ----
    gcn_gather_vec<80><<<divup(N_NODESC * 10, TPB), TPB, 0, stream>>>(
        xbf, row_ptr, csr_src, dinv, aggbuf, N_NODESC);
    gemm_mfma<78, 80, 156, 160, true><<<dim3(divup(N_NODESC, 64), 3), 256, 0, stream>>>(
        aggbuf, Wt2, b2, hbuf, N_NODESC);

    // ---- GCN layer 3: agg(h2) -> gemm -> h3 (LD 312) ----
    gcn_gather_vec<160><<<divup(N_NODESC * 20, TPB), TPB, 0, stream>>>(
        hbuf, row_ptr, csr_src, dinv, aggbuf, N_NODESC);
    gemm_mfma<156, 160, 312, 312, true><<<dim3(divup(N_NODESC, 64), 5), 256, 0, stream>>>(
        aggbuf, Wt3, b3, hbuf, N_NODESC);

    // ---- global max pool ----
    seg_max<<<NBATCH, 320, 0, stream>>>(hbuf, bptr, g0);

    // ---- graph head (fp32) ----
    gemm_tiled<312, 1024, true, true><<<dim3(divup(NBATCH, 64), 16), 256, 0, stream>>>(
        g0, Wg1, bg1, g1, NBATCH, 1024, 0);
    gemm_tiled<1024, 128, false, true><<<dim3(divup(NBATCH, 64), 2), 256, 0, stream>>>(
        g1, Wg2, bg2, xc, NBATCH, 256, 0);

    // ---- protein branch: implicit-GEMM conv ----
    conv_gemm<<<dim3(6144 / 64, CONV_KSPLIT), 256, 0, stream>>>(T, Kxt, cpart);
    conv_reduce<<<divup(NBATCH * 384, TPB), TPB, 0, stream>>>(cpart, bxt, convb);
    gemm_tiled<384, 128, false, true><<<dim3(divup(NBATCH, 64), 2), 256, 0, stream>>>(
        convb, Wxt, bxt2, xc, NBATCH, 256, 128);

    // ---- fusion MLP ----
    gemm_tiled<256, 1024, true, true><<<dim3(divup(NBATCH, 64), 16), 256, 0, stream>>>(
        xc, Wf1, bf1, f1, NBATCH, 1024, 0);
    gemm_tiled<1024, 512, true, true><<<dim3(divup(NBATCH, 64), 8), 256, 0, stream>>>(
        f1, Wf2, bf2, f2, NBATCH, 512, 0);
    final_out<<<divup(NBATCH, 4), 256, 0, stream>>>(f2, Wo, bo, out);
}

// Round 8
// 592.630 us; speedup vs baseline: 2.5624x; 1.6851x over previous
//
#include <hip/hip_runtime.h>
#include <hip/hip_bf16.h>
#include <cstddef>
#include <cstdint>

#define N_NODESC 100000
#define N_EDGESC 500000
#define NBATCH   512
#define SCAN_CHUNK 1024
#define CONV_KSPLIT 4
#define CONV_KCHUNK 1504   // multiple of 32 -> k-octets stay channel-aligned

static inline int divup(int a, int b) { return (a + b - 1) / b; }

typedef __hip_bfloat16 bf16;
typedef short s16x8 __attribute__((ext_vector_type(8)));
typedef float f32x4 __attribute__((ext_vector_type(4)));

__device__ inline float b2f(ushort u) {
    union { uint i; float f; } c; c.i = (uint)u << 16; return c.f;
}
__device__ inline ushort f2bs(float v) {
    bf16 b = __float2bfloat16(v);
    return *reinterpret_cast<ushort*>(&b);
}
__device__ inline void unpack2(uint u, float& a, float& b) {
    union { uint i; float f; } lo, hi;
    lo.i = u << 16; hi.i = u & 0xffff0000u;
    a = lo.f; b = hi.f;
}

// ---------------- zero ints ----------------
__global__ void zero_ints(int* __restrict__ p, int n) {
    int i = blockIdx.x * blockDim.x + threadIdx.x;
    if (i < n) p[i] = 0;
}

// ---------------- degree / dinv ----------------
__global__ void count_deg(const int* __restrict__ dst, int* __restrict__ deg, int e) {
    int i = blockIdx.x * blockDim.x + threadIdx.x;
    if (i < e) atomicAdd(&deg[dst[i]], 1);
}

__global__ void compute_dinv(const int* __restrict__ deg, float* __restrict__ dinv, int n) {
    int i = blockIdx.x * blockDim.x + threadIdx.x;
    if (i < n) dinv[i] = 1.0f / sqrtf((float)deg[i] + 1.0f);
}

// ---------------- exclusive scan (3-phase) ----------------
__global__ void scan_chunks(const int* __restrict__ deg, int* __restrict__ out,
                            int* __restrict__ sums, int n) {
    __shared__ int sdata[256];
    int t = threadIdx.x;
    int base = blockIdx.x * SCAN_CHUNK;
    int v[4];
    int s = 0;
#pragma unroll
    for (int j = 0; j < 4; ++j) {
        int idx = base + t * 4 + j;
        v[j] = s;
        int d = (idx < n) ? deg[idx] : 0;
        s += d;
    }
    int x = s;
    sdata[t] = x;
    __syncthreads();
    for (int off = 1; off < 256; off <<= 1) {
        int y = (t >= off) ? sdata[t - off] : 0;
        __syncthreads();
        x += y;
        sdata[t] = x;
        __syncthreads();
    }
    int thread_excl = x - s;
    if (t == 255) sums[blockIdx.x] = x;
#pragma unroll
    for (int j = 0; j < 4; ++j) {
        int idx = base + t * 4 + j;
        if (idx < n) out[idx] = thread_excl + v[j];
    }
}

__global__ void scan_sums(int* sums, int nchunks) {
    if (threadIdx.x == 0 && blockIdx.x == 0) {
        int acc = 0;
        for (int i = 0; i < nchunks; ++i) { int v = sums[i]; sums[i] = acc; acc += v; }
    }
}

__global__ void finalize_rowptr(int* __restrict__ row_ptr, const int* __restrict__ sums,
                                int* __restrict__ fill, int n, int e) {
    int i = blockIdx.x * blockDim.x + threadIdx.x;
    if (i < n) {
        int v = row_ptr[i] + sums[i / SCAN_CHUNK];
        row_ptr[i] = v;
        fill[i] = v;
    }
    if (i == 0) row_ptr[n] = e;
}

__global__ void fill_csr(const int* __restrict__ src, const int* __restrict__ dst,
                         int* __restrict__ fill, int* __restrict__ csr_src, int e) {
    int i = blockIdx.x * blockDim.x + threadIdx.x;
    if (i < e) {
        int d = dst[i];
        int pos = atomicAdd(&fill[d], 1);
        csr_src[pos] = src[i];
    }
}

// ---------------- batch segment pointers (batch is sorted) ----------------
__global__ void build_batch_ptr(const int* __restrict__ batch, int* __restrict__ bptr,
                                int n, int nb) {
    int i = blockIdx.x * blockDim.x + threadIdx.x;
    if (i >= n) return;
    int b = batch[i];
    int prev = (i == 0) ? -1 : batch[i - 1];
    for (int bb = prev + 1; bb <= b; ++bb) bptr[bb] = i;
    if (i == n - 1) {
        for (int bb = b + 1; bb <= nb; ++bb) bptr[bb] = n;
    }
}

// ---------------- fp32 -> bf16 node-feature conversion with padded stride ----------------
__global__ void convert_x_bf16(const float* __restrict__ x, ushort* __restrict__ xbf,
                               int n, int ki, int ld) {
    int i = blockIdx.x * blockDim.x + threadIdx.x;
    int total = n * ld;
    if (i >= total) return;
    int node = i / ld, col = i % ld;
    xbf[i] = (col < ki) ? f2bs(x[(size_t)node * ki + col]) : (ushort)0;
}

// ---------------- W[KI,KO] fp32 -> Wt[KO,LD] bf16 (transposed, zero-padded) ----------------
__global__ void transpose_w_bf16(const float* __restrict__ W, ushort* __restrict__ Wt,
                                 int ki, int ko, int ld) {
    int i = blockIdx.x * blockDim.x + threadIdx.x;
    int total = ko * ld;
    if (i >= total) return;
    int o = i / ld, k = i % ld;
    Wt[i] = (k < ki) ? f2bs(W[(size_t)k * ko + o]) : (ushort)0;
}

// ---------------- vectorized GCN aggregation: agg = \hat{A} h ----------------
template <int LD>
__global__ void gcn_gather_vec(const ushort* __restrict__ h, const int* __restrict__ row_ptr,
                               const int* __restrict__ csr_src, const float* __restrict__ dinv,
                               ushort* __restrict__ agg, int n) {
    constexpr int TPN = LD / 8;
    int gid = blockIdx.x * blockDim.x + threadIdx.x;
    int node = gid / TPN, oct = gid % TPN;
    if (node >= n) return;
    float dn = dinv[node];
    int e0 = row_ptr[node], e1 = row_ptr[node + 1];
    float acc[8];
    {   // self loop: dinv^2 * h[node]
        uint4 v = *reinterpret_cast<const uint4*>(&h[(size_t)node * LD + oct * 8]);
        float w = dn * dn;
        float a, b;
        unpack2(v.x, a, b); acc[0] = a * w; acc[1] = b * w;
        unpack2(v.y, a, b); acc[2] = a * w; acc[3] = b * w;
        unpack2(v.z, a, b); acc[4] = a * w; acc[5] = b * w;
        unpack2(v.w, a, b); acc[6] = a * w; acc[7] = b * w;
    }
    for (int e = e0; e < e1; ++e) {
        int s = csr_src[e];
        float w = dinv[s] * dn;
        uint4 v = *reinterpret_cast<const uint4*>(&h[(size_t)s * LD + oct * 8]);
        float a, b;
        unpack2(v.x, a, b); acc[0] = fmaf(a, w, acc[0]); acc[1] = fmaf(b, w, acc[1]);
        unpack2(v.y, a, b); acc[2] = fmaf(a, w, acc[2]); acc[3] = fmaf(b, w, acc[3]);
        unpack2(v.z, a, b); acc[4] = fmaf(a, w, acc[4]); acc[5] = fmaf(b, w, acc[5]);
        unpack2(v.w, a, b); acc[6] = fmaf(a, w, acc[6]); acc[7] = fmaf(b, w, acc[7]);
    }
    uint4 o;
    o.x = (uint)f2bs(acc[0]) | ((uint)f2bs(acc[1]) << 16);
    o.y = (uint)f2bs(acc[2]) | ((uint)f2bs(acc[3]) << 16);
    o.z = (uint)f2bs(acc[4]) | ((uint)f2bs(acc[5]) << 16);
    o.w = (uint)f2bs(acc[6]) | ((uint)f2bs(acc[7]) << 16);
    *reinterpret_cast<uint4*>(&agg[(size_t)node * LD + oct * 8]) = o;
}

// ---------------- bf16 MFMA GEMM: C = A @ Wt^T (+bias)(+relu), bf16 out ----------------
template <int KI, int LDA, int KO, int LDC, bool BIASRELU>
__global__ __launch_bounds__(256) void gemm_mfma(const ushort* __restrict__ A,
                                                 const ushort* __restrict__ Bt,
                                                 const float* __restrict__ bias,
                                                 ushort* __restrict__ C, int n) {
    __shared__ ushort sA[64][40];
    __shared__ ushort sB[64][40];
    const int t = threadIdx.x;
    const int row0 = blockIdx.x * 64;
    const int col0 = blockIdx.y * 64;
    const int wid = t >> 6, lane = t & 63;
    const int wr = wid >> 1, wc = wid & 1;
    const int lrow = lane & 15;
    const int kgrp = lane >> 4;
    const int srr = t >> 2;      // staging row 0..63
    const int skq = t & 3;       // staging k-octet
    f32x4 acc[2][2];
#pragma unroll
    for (int i = 0; i < 2; ++i)
#pragma unroll
        for (int j = 0; j < 2; ++j) acc[i][j] = (f32x4)0.f;

    const int nk = (KI + 31) / 32;
    for (int ks = 0; ks < nk; ++ks) {
        const int kbase = ks * 32 + skq * 8;
        {   // stage A tile (64 rows x 32 k)
            int grow = row0 + srr;
            uint4 v = {0, 0, 0, 0};
            if (grow < n && kbase < LDA)
                v = *reinterpret_cast<const uint4*>(&A[(size_t)grow * LDA + kbase]);
            *reinterpret_cast<uint4*>(&sA[srr][skq * 8]) = v;
        }
        {   // stage B tile (64 cols x 32 k)
            int gcol = col0 + srr;
            uint4 v = {0, 0, 0, 0};
            if (gcol < KO && kbase < LDA)
                v = *reinterpret_cast<const uint4*>(&Bt[(size_t)gcol * LDA + kbase]);
            *reinterpret_cast<uint4*>(&sB[srr][skq * 8]) = v;
        }
        __syncthreads();
        s16x8 a0 = *reinterpret_cast<const s16x8*>(&sA[wr * 32 + lrow][kgrp * 8]);
        s16x8 a1 = *reinterpret_cast<const s16x8*>(&sA[wr * 32 + 16 + lrow][kgrp * 8]);
        s16x8 b0 = *reinterpret_cast<const s16x8*>(&sB[wc * 32 + lrow][kgrp * 8]);
        s16x8 b1 = *reinterpret_cast<const s16x8*>(&sB[wc * 32 + 16 + lrow][kgrp * 8]);
        acc[0][0] = __builtin_amdgcn_mfma_f32_16x16x32_bf16(a0, b0, acc[0][0], 0, 0, 0);
        acc[0][1] = __builtin_amdgcn_mfma_f32_16x16x32_bf16(a0, b1, acc[0][1], 0, 0, 0);
        acc[1][0] = __builtin_amdgcn_mfma_f32_16x16x32_bf16(a1, b0, acc[1][0], 0, 0, 0);
        acc[1][1] = __builtin_amdgcn_mfma_f32_16x16x32_bf16(a1, b1, acc[1][1], 0, 0, 0);
        __syncthreads();
    }
#pragma unroll
    for (int fr = 0; fr < 2; ++fr)
#pragma unroll
        for (int fc = 0; fc < 2; ++fc)
#pragma unroll
            for (int r = 0; r < 4; ++r) {
                int row = row0 + wr * 32 + fr * 16 + kgrp * 4 + r;
                int col = col0 + wc * 32 + fc * 16 + lrow;
                if (row < n && col < LDC) {
                    float v = acc[fr][fc][r];
                    ushort o = 0;
                    if (col < KO) {
                        if (BIASRELU) v = fmaxf(v + bias[col], 0.f);
                        o = f2bs(v);
                    }
                    C[(size_t)row * LDC + col] = o;
                }
            }
}

// ---------------- segment max pool (batch segments) ----------------
__global__ void seg_max(const ushort* __restrict__ h, const int* __restrict__ bptr,
                        float* __restrict__ g) {
    int b = blockIdx.x;
    int f = threadIdx.x;
    if (f >= 312) return;
    int n0 = bptr[b], n1 = bptr[b + 1];
    float m = -INFINITY;
    for (int n = n0; n < n1; ++n) m = fmaxf(m, b2f(h[(size_t)n * 312 + f]));
    g[(size_t)b * 312 + f] = m;
}

// ---------------- head GEMM: K-split, 32x64 tile, fp32 partials ----------------
// partial[z][row][col] (col within full KO). Grid: (n/32, KO/64, nsplit).
// LDS strides: sA 34 floats (136B, 8B-aligned at even r0); sW 68 floats (272B, 16B-aligned at c0*4).
template <int KI, int KO, int KS>
__global__ __launch_bounds__(256) void gemm_head(const float* __restrict__ A,
                                                 const float* __restrict__ W,
                                                 float* __restrict__ partial, int n) {
    __shared__ float sA[16][34];
    __shared__ float sW[16][68];
    const int t = threadIdx.x;
    const int row0 = blockIdx.x * 32;
    const int col0 = blockIdx.y * 64;
    const int z = blockIdx.z;
    const int kbeg = z * KS;
    const int kend = min(KI, kbeg + KS);
    const int r0 = (t >> 4) * 2;   // 0..30 (even)
    const int c0 = (t & 15) * 4;   // 0..60 (quad)
    float acc[2][4] = {};
    for (int k0 = kbeg; k0 < kend; k0 += 16) {
        {   // stage A: 32 rows x 16 k; thread -> (row = t>>3, k pair = (t&7)*2)
            int row = t >> 3, kk = (t & 7) * 2;
            int grow = row0 + row;
#pragma unroll
            for (int j = 0; j < 2; ++j) {
                float v = 0.f;
                if (grow < n && (k0 + kk + j) < kend) v = A[(size_t)grow * KI + k0 + kk + j];
                sA[kk + j][row] = v;
            }
        }
        {   // stage W: 16 k x 64 cols; thread -> (k = t>>4, col quad = (t&15)*4)
            int kk = t >> 4, cc = (t & 15) * 4;
#pragma unroll
            for (int j = 0; j < 4; ++j) {
                float v = 0.f;
                if ((k0 + kk) < kend) v = W[(size_t)(k0 + kk) * KO + col0 + cc + j];
                sW[kk][cc + j] = v;
            }
        }
        __syncthreads();
#pragma unroll 8
        for (int k = 0; k < 16; ++k) {
            float2 a = *reinterpret_cast<const float2*>(&sA[k][r0]);
            float4 w = *reinterpret_cast<const float4*>(&sW[k][c0]);
            acc[0][0] = fmaf(a.x, w.x, acc[0][0]); acc[0][1] = fmaf(a.x, w.y, acc[0][1]);
            acc[0][2] = fmaf(a.x, w.z, acc[0][2]); acc[0][3] = fmaf(a.x, w.w, acc[0][3]);
            acc[1][0] = fmaf(a.y, w.x, acc[1][0]); acc[1][1] = fmaf(a.y, w.y, acc[1][1]);
            acc[1][2] = fmaf(a.y, w.z, acc[1][2]); acc[1][3] = fmaf(a.y, w.w, acc[1][3]);
        }
        __syncthreads();
    }
#pragma unroll
    for (int ri = 0; ri < 2; ++ri) {
        int row = row0 + r0 + ri;
        if (row >= n) continue;
        *reinterpret_cast<float4*>(&partial[((size_t)z * n + row) * KO + col0 + c0]) =
            make_float4(acc[ri][0], acc[ri][1], acc[ri][2], acc[ri][3]);
    }
}

// sum partials over splits + bias (+relu), scatter into C[row*ldc + col_off + col]
template <int NS, bool RELU>
__global__ void head_reduce(const float* __restrict__ partial, const float* __restrict__ bias,
                            float* __restrict__ C, int n, int KO, int ldc, int col_off) {
    int j = blockIdx.x * blockDim.x + threadIdx.x;
    if (j >= n * KO) return;
    int row = j / KO, col = j % KO;
    float acc = bias[col];
#pragma unroll
    for (int s = 0; s < NS; ++s) acc += partial[((size_t)s * n + row) * KO + col];
    if (RELU) acc = fmaxf(acc, 0.f);
    C[(size_t)row * ldc + col_off + col] = acc;
}

// ---------------- Conv1d as implicit GEMM, K-split ----------------
__global__ __launch_bounds__(256) void conv_gemm(const float* __restrict__ T,
                                                 const float* __restrict__ Kxt,
                                                 float* __restrict__ partial) {
    __shared__ float sA[32][66];
    __shared__ float sW[32][36];
    const int t = threadIdx.x;
    const int row0 = blockIdx.x * 64;
    const int split = blockIdx.y;
    const int kbeg = split * CONV_KCHUNK;
    const int kend = min(6000, kbeg + CONV_KCHUNK);
    const int r0 = (t >> 3) * 2;   // row pair (even)
    const int c0 = (t & 7) * 4;    // col quad
    float acc[2][4] = {};
    for (int k0 = kbeg; k0 < kend; k0 += 32) {
        {   // stage A: thread -> row rr, k-octet kq   (kb is a multiple of 8)
            int rr = t >> 2, kq = t & 3;
            int grow = row0 + rr;                 // < 6144 always
            int b = grow / 12, h = grow % 12;
            int kb = k0 + kq * 8;
            int i = kb >> 3;
            const float* tp = &T[(size_t)b * 14250 + (size_t)i * 19 + h];
#pragma unroll
            for (int j = 0; j < 8; ++j)
                sA[kq * 8 + j][rr] = (kb + j < kend) ? tp[j] : 0.f;
        }
        {   // stage B: thread -> k = t&31, o-quad (t>>5)*4
            int kk = t & 31, ob = (t >> 5) * 4;
            int gk = k0 + kk;
#pragma unroll
            for (int j = 0; j < 4; ++j)
                sW[kk][ob + j] = (gk < kend) ? Kxt[(size_t)(ob + j) * 6000 + gk] : 0.f;
        }
        __syncthreads();
#pragma unroll 8
        for (int k = 0; k < 32; ++k) {
            float2 a = *reinterpret_cast<const float2*>(&sA[k][r0]);
            float4 w = *reinterpret_cast<const float4*>(&sW[k][c0]);
            acc[0][0] = fmaf(a.x, w.x, acc[0][0]); acc[0][1] = fmaf(a.x, w.y, acc[0][1]);
            acc[0][2] = fmaf(a.x, w.z, acc[0][2]); acc[0][3] = fmaf(a.x, w.w, acc[0][3]);
            acc[1][0] = fmaf(a.y, w.x, acc[1][0]); acc[1][1] = fmaf(a.y, w.y, acc[1][1]);
            acc[1][2] = fmaf(a.y, w.z, acc[1][2]); acc[1][3] = fmaf(a.y, w.w, acc[1][3]);
        }
        __syncthreads();
    }
#pragma unroll
    for (int ri = 0; ri < 2; ++ri) {
        int row = row0 + r0 + ri;
        int b = row / 12, h = row % 12;
#pragma unroll
        for (int j = 0; j < 4; ++j)
            partial[(((size_t)split * NBATCH + b) * 32 + (c0 + j)) * 12 + h] = acc[ri][j];
    }
}

__global__ void conv_reduce(const float* __restrict__ partial, const float* __restrict__ bxt,
                            float* __restrict__ convb) {
    int j = blockIdx.x * blockDim.x + threadIdx.x;
    if (j >= NBATCH * 384) return;
    int b = j / 384, rem = j % 384;
    int o = rem / 12, h = rem % 12;
    float acc = bxt[o];
#pragma unroll
    for (int s = 0; s < CONV_KSPLIT; ++s)
        acc += partial[(((size_t)s * NBATCH + b) * 32 + o) * 12 + h];
    convb[j] = acc;
}

// ---------------- final [512,512] @ [512,1] ----------------
__global__ void final_out(const float* __restrict__ f2, const float* __restrict__ Wo,
                          const float* __restrict__ bo, float* __restrict__ out) {
    int row = blockIdx.x * (blockDim.x / 64) + (threadIdx.x / 64);
    int lane = threadIdx.x & 63;
    if (row >= NBATCH) return;
    float acc = 0.f;
    for (int k = lane; k < 512; k += 64) acc = fmaf(f2[(size_t)row * 512 + k], Wo[k], acc);
#pragma unroll
    for (int off = 32; off > 0; off >>= 1) acc += __shfl_down(acc, off);
    if (lane == 0) out[row] = acc + bo[0];
}

extern "C" void kernel_launch(void* const* d_in, const int* in_sizes, int n_in,
                              void* d_out, int out_size, void* d_ws, size_t ws_size,
                              hipStream_t stream) {
    (void)in_sizes; (void)n_in; (void)out_size; (void)ws_size;
    const float* x     = (const float*)d_in[0];
    const int*   ei    = (const int*)d_in[1];
    const int*   batch = (const int*)d_in[2];
    const float* T     = (const float*)d_in[3];
    const float* W1 = (const float*)d_in[4];   const float* b1 = (const float*)d_in[5];
    const float* W2 = (const float*)d_in[6];   const float* b2 = (const float*)d_in[7];
    const float* W3 = (const float*)d_in[8];   const float* b3 = (const float*)d_in[9];
    const float* Wg1 = (const float*)d_in[10]; const float* bg1 = (const float*)d_in[11];
    const float* Wg2 = (const float*)d_in[12]; const float* bg2 = (const float*)d_in[13];
    const float* Kxt = (const float*)d_in[14]; const float* bxt = (const float*)d_in[15];
    const float* Wxt = (const float*)d_in[16]; const float* bxt2 = (const float*)d_in[17];
    const float* Wf1 = (const float*)d_in[18]; const float* bf1 = (const float*)d_in[19];
    const float* Wf2 = (const float*)d_in[20]; const float* bf2 = (const float*)d_in[21];
    const float* Wo = (const float*)d_in[22];  const float* bo = (const float*)d_in[23];
    const int* src = ei;
    const int* dst = ei + N_EDGESC;

    char* ws = (char*)d_ws;
    size_t off = 0;
    auto alloc = [&](size_t bytes) -> void* {
        void* p = ws + off;
        off += (bytes + 255) & ~(size_t)255;
        return p;
    };
    // ~128 MB total
    int*   deg      = (int*)alloc((size_t)N_NODESC * 4);
    float* dinv     = (float*)alloc((size_t)N_NODESC * 4);
    int*   row_ptr  = (int*)alloc((size_t)(N_NODESC + 1) * 4);
    int*   fillc    = (int*)alloc((size_t)N_NODESC * 4);
    int*   csr_src  = (int*)alloc((size_t)N_EDGESC * 4);
    int*   csums    = (int*)alloc((size_t)4096 * 4);
    int*   bptr     = (int*)alloc((size_t)(NBATCH + 1) * 4);
    float* g0       = (float*)alloc((size_t)NBATCH * 312 * 4);
    float* g1       = (float*)alloc((size_t)NBATCH * 1024 * 4);
    float* convb    = (float*)alloc((size_t)NBATCH * 384 * 4);
    float* xc       = (float*)alloc((size_t)NBATCH * 256 * 4);
    float* f1       = (float*)alloc((size_t)NBATCH * 1024 * 4);
    float* f2       = (float*)alloc((size_t)NBATCH * 512 * 4);
    float* cpart    = (float*)alloc((size_t)CONV_KSPLIT * NBATCH * 32 * 12 * 4);
    float* hpart    = (float*)alloc((size_t)8 * NBATCH * 128 * 4);  // 2MB: all head splits fit
    ushort* xbf     = (ushort*)alloc((size_t)N_NODESC * 80 * 2);   // x (80) -> later h1 (80)
    ushort* aggbuf  = (ushort*)alloc((size_t)N_NODESC * 160 * 2);  // agg1/2 (80), agg3 (160)
    ushort* hbuf    = (ushort*)alloc((size_t)N_NODESC * 312 * 2);  // h2 (160), h3 (312)
    ushort* Wt1     = (ushort*)alloc((size_t)78 * 80 * 2);
    ushort* Wt2     = (ushort*)alloc((size_t)156 * 80 * 2);
    ushort* Wt3     = (ushort*)alloc((size_t)312 * 160 * 2);
    float* out      = (float*)d_out;

    const int TPB = 256;

    // ---- graph structure ----
    zero_ints<<<divup(N_NODESC, TPB), TPB, 0, stream>>>(deg, N_NODESC);
    count_deg<<<divup(N_EDGESC, TPB), TPB, 0, stream>>>(dst, deg, N_EDGESC);
    compute_dinv<<<divup(N_NODESC, TPB), TPB, 0, stream>>>(deg, dinv, N_NODESC);
    int nchunks = divup(N_NODESC, SCAN_CHUNK);
    scan_chunks<<<nchunks, 256, 0, stream>>>(deg, row_ptr, csums, N_NODESC);
    scan_sums<<<1, 64, 0, stream>>>(csums, nchunks);
    finalize_rowptr<<<divup(N_NODESC, TPB), TPB, 0, stream>>>(row_ptr, csums, fillc, N_NODESC, N_EDGESC);
    fill_csr<<<divup(N_EDGESC, TPB), TPB, 0, stream>>>(src, dst, fillc, csr_src, N_EDGESC);
    build_batch_ptr<<<divup(N_NODESC, TPB), TPB, 0, stream>>>(batch, bptr, N_NODESC, NBATCH);

    // ---- bf16 conversions ----
    convert_x_bf16<<<divup(N_NODESC * 80, TPB), TPB, 0, stream>>>(x, xbf, N_NODESC, 78, 80);
    transpose_w_bf16<<<divup(78 * 80, TPB), TPB, 0, stream>>>(W1, Wt1, 78, 78, 80);
    transpose_w_bf16<<<divup(156 * 80, TPB), TPB, 0, stream>>>(W2, Wt2, 78, 156, 80);
    transpose_w_bf16<<<divup(312 * 160, TPB), TPB, 0, stream>>>(W3, Wt3, 156, 312, 160);

    // ---- GCN layer 1: agg(x) -> gemm+bias+relu -> h1 (LD 80) ----
    gcn_gather_vec<80><<<divup(N_NODESC * 10, TPB), TPB, 0, stream>>>(
        xbf, row_ptr, csr_src, dinv, aggbuf, N_NODESC);
    gemm_mfma<78, 80, 78, 80, true><<<dim3(divup(N_NODESC, 64), 2), 256, 0, stream>>>(
        aggbuf, Wt1, b1, xbf, N_NODESC);   // h1 overwrites xbf (x dead)

    // ---- GCN layer 2: agg(h1) -> gemm -> h2 (LD 160) ----
    gcn_gather_vec<80><<<divup(N_NODESC * 10, TPB), TPB, 0, stream>>>(
        xbf, row_ptr, csr_src, dinv, aggbuf, N_NODESC);
    gemm_mfma<78, 80, 156, 160, true><<<dim3(divup(N_NODESC, 64), 3), 256, 0, stream>>>(
        aggbuf, Wt2, b2, hbuf, N_NODESC);

    // ---- GCN layer 3: agg(h2) -> gemm -> h3 (LD 312) ----
    gcn_gather_vec<160><<<divup(N_NODESC * 20, TPB), TPB, 0, stream>>>(
        hbuf, row_ptr, csr_src, dinv, aggbuf, N_NODESC);
    gemm_mfma<156, 160, 312, 312, true><<<dim3(divup(N_NODESC, 64), 5), 256, 0, stream>>>(
        aggbuf, Wt3, b3, hbuf, N_NODESC);

    // ---- global max pool ----
    seg_max<<<NBATCH, 320, 0, stream>>>(hbuf, bptr, g0);

    // ---- graph head: g1 = relu(g0 @ Wg1 + bg1) ----
    gemm_head<312, 1024, 312><<<dim3(16, 16, 1), 256, 0, stream>>>(g0, Wg1, hpart, NBATCH);
    head_reduce<1, true><<<divup(NBATCH * 1024, TPB), TPB, 0, stream>>>(
        hpart, bg1, g1, NBATCH, 1024, 1024, 0);
    // xc[:, :128] = g1 @ Wg2 + bg2
    gemm_head<1024, 128, 128><<<dim3(16, 2, 8), 256, 0, stream>>>(g1, Wg2, hpart, NBATCH);
    head_reduce<8, false><<<divup(NBATCH * 128, TPB), TPB, 0, stream>>>(
        hpart, bg2, xc, NBATCH, 128, 256, 0);

    // ---- protein branch: implicit-GEMM conv ----
    conv_gemm<<<dim3(6144 / 64, CONV_KSPLIT), 256, 0, stream>>>(T, Kxt, cpart);
    conv_reduce<<<divup(NBATCH * 384, TPB), TPB, 0, stream>>>(cpart, bxt, convb);
    // xc[:, 128:] = convb @ Wxt + bxt2
    gemm_head<384, 128, 48><<<dim3(16, 2, 8), 256, 0, stream>>>(convb, Wxt, hpart, NBATCH);
    head_reduce<8, false><<<divup(NBATCH * 128, TPB), TPB, 0, stream>>>(
        hpart, bxt2, xc, NBATCH, 128, 256, 128);

    // ---- fusion MLP ----
    gemm_head<256, 1024, 256><<<dim3(16, 16, 1), 256, 0, stream>>>(xc, Wf1, hpart, NBATCH);
    head_reduce<1, true><<<divup(NBATCH * 1024, TPB), TPB, 0, stream>>>(
        hpart, bf1, f1, NBATCH, 1024, 1024, 0);
    gemm_head<1024, 512, 512><<<dim3(16, 8, 2), 256, 0, stream>>>(f1, Wf2, hpart, NBATCH);
    head_reduce<2, true><<<divup(NBATCH * 512, TPB), TPB, 0, stream>>>(
        hpart, bf2, f2, NBATCH, 512, 512, 0);
    final_out<<<divup(NBATCH, 4), 256, 0, stream>>>(f2, Wo, bo, out);
}

// Round 9
// 533.168 us; speedup vs baseline: 2.8482x; 1.1115x over previous
//
#include <hip/hip_runtime.h>
#include <hip/hip_bf16.h>
#include <cstddef>
#include <cstdint>

#define N_NODESC 100000
#define N_EDGESC 500000
#define NBATCH   512
#define SCAN_CHUNK 1024
#define CONV_KSPLIT 16
#define CONV_KCHUNK 384    // multiple of 32 -> k-octets stay channel-aligned; last split ragged (240)

static inline int divup(int a, int b) { return (a + b - 1) / b; }

typedef __hip_bfloat16 bf16;
typedef short s16x8 __attribute__((ext_vector_type(8)));
typedef float f32x4 __attribute__((ext_vector_type(4)));

__device__ inline float b2f(ushort u) {
    union { uint i; float f; } c; c.i = (uint)u << 16; return c.f;
}
__device__ inline ushort f2bs(float v) {
    bf16 b = __float2bfloat16(v);
    return *reinterpret_cast<ushort*>(&b);
}
__device__ inline void unpack2(uint u, float& a, float& b) {
    union { uint i; float f; } lo, hi;
    lo.i = u << 16; hi.i = u & 0xffff0000u;
    a = lo.f; b = hi.f;
}

// ---------------- zero ints ----------------
__global__ void zero_ints(int* __restrict__ p, int n) {
    int i = blockIdx.x * blockDim.x + threadIdx.x;
    if (i < n) p[i] = 0;
}

// ---------------- degree / dinv ----------------
__global__ void count_deg(const int* __restrict__ dst, int* __restrict__ deg, int e) {
    int i = blockIdx.x * blockDim.x + threadIdx.x;
    if (i < e) atomicAdd(&deg[dst[i]], 1);
}

__global__ void compute_dinv(const int* __restrict__ deg, float* __restrict__ dinv, int n) {
    int i = blockIdx.x * blockDim.x + threadIdx.x;
    if (i < n) dinv[i] = 1.0f / sqrtf((float)deg[i] + 1.0f);
}

// ---------------- exclusive scan (3-phase) ----------------
__global__ void scan_chunks(const int* __restrict__ deg, int* __restrict__ out,
                            int* __restrict__ sums, int n) {
    __shared__ int sdata[256];
    int t = threadIdx.x;
    int base = blockIdx.x * SCAN_CHUNK;
    int v[4];
    int s = 0;
#pragma unroll
    for (int j = 0; j < 4; ++j) {
        int idx = base + t * 4 + j;
        v[j] = s;
        int d = (idx < n) ? deg[idx] : 0;
        s += d;
    }
    int x = s;
    sdata[t] = x;
    __syncthreads();
    for (int off = 1; off < 256; off <<= 1) {
        int y = (t >= off) ? sdata[t - off] : 0;
        __syncthreads();
        x += y;
        sdata[t] = x;
        __syncthreads();
    }
    int thread_excl = x - s;
    if (t == 255) sums[blockIdx.x] = x;
#pragma unroll
    for (int j = 0; j < 4; ++j) {
        int idx = base + t * 4 + j;
        if (idx < n) out[idx] = thread_excl + v[j];
    }
}

__global__ void scan_sums(int* sums, int nchunks) {
    if (threadIdx.x == 0 && blockIdx.x == 0) {
        int acc = 0;
        for (int i = 0; i < nchunks; ++i) { int v = sums[i]; sums[i] = acc; acc += v; }
    }
}

__global__ void finalize_rowptr(int* __restrict__ row_ptr, const int* __restrict__ sums,
                                int* __restrict__ fill, int n, int e) {
    int i = blockIdx.x * blockDim.x + threadIdx.x;
    if (i < n) {
        int v = row_ptr[i] + sums[i / SCAN_CHUNK];
        row_ptr[i] = v;
        fill[i] = v;
    }
    if (i == 0) row_ptr[n] = e;
}

__global__ void fill_csr(const int* __restrict__ src, const int* __restrict__ dst,
                         int* __restrict__ fill, int* __restrict__ csr_src, int e) {
    int i = blockIdx.x * blockDim.x + threadIdx.x;
    if (i < e) {
        int d = dst[i];
        int pos = atomicAdd(&fill[d], 1);
        csr_src[pos] = src[i];
    }
}

// ---------------- batch segment pointers (batch is sorted) ----------------
__global__ void build_batch_ptr(const int* __restrict__ batch, int* __restrict__ bptr,
                                int n, int nb) {
    int i = blockIdx.x * blockDim.x + threadIdx.x;
    if (i >= n) return;
    int b = batch[i];
    int prev = (i == 0) ? -1 : batch[i - 1];
    for (int bb = prev + 1; bb <= b; ++bb) bptr[bb] = i;
    if (i == n - 1) {
        for (int bb = b + 1; bb <= nb; ++bb) bptr[bb] = n;
    }
}

// ---------------- fp32 -> bf16 node-feature conversion with padded stride ----------------
__global__ void convert_x_bf16(const float* __restrict__ x, ushort* __restrict__ xbf,
                               int n, int ki, int ld) {
    int i = blockIdx.x * blockDim.x + threadIdx.x;
    int total = n * ld;
    if (i >= total) return;
    int node = i / ld, col = i % ld;
    xbf[i] = (col < ki) ? f2bs(x[(size_t)node * ki + col]) : (ushort)0;
}

// ---------------- W[KI,KO] fp32 -> Wt[KO,LD] bf16 (transposed, zero-padded) ----------------
__global__ void transpose_w_bf16(const float* __restrict__ W, ushort* __restrict__ Wt,
                                 int ki, int ko, int ld) {
    int i = blockIdx.x * blockDim.x + threadIdx.x;
    int total = ko * ld;
    if (i >= total) return;
    int o = i / ld, k = i % ld;
    Wt[i] = (k < ki) ? f2bs(W[(size_t)k * ko + o]) : (ushort)0;
}

// ---------------- vectorized GCN aggregation: agg = \hat{A} h ----------------
template <int LD>
__global__ void gcn_gather_vec(const ushort* __restrict__ h, const int* __restrict__ row_ptr,
                               const int* __restrict__ csr_src, const float* __restrict__ dinv,
                               ushort* __restrict__ agg, int n) {
    constexpr int TPN = LD / 8;
    int gid = blockIdx.x * blockDim.x + threadIdx.x;
    int node = gid / TPN, oct = gid % TPN;
    if (node >= n) return;
    float dn = dinv[node];
    int e0 = row_ptr[node], e1 = row_ptr[node + 1];
    float acc[8];
    {   // self loop: dinv^2 * h[node]
        uint4 v = *reinterpret_cast<const uint4*>(&h[(size_t)node * LD + oct * 8]);
        float w = dn * dn;
        float a, b;
        unpack2(v.x, a, b); acc[0] = a * w; acc[1] = b * w;
        unpack2(v.y, a, b); acc[2] = a * w; acc[3] = b * w;
        unpack2(v.z, a, b); acc[4] = a * w; acc[5] = b * w;
        unpack2(v.w, a, b); acc[6] = a * w; acc[7] = b * w;
    }
    for (int e = e0; e < e1; ++e) {
        int s = csr_src[e];
        float w = dinv[s] * dn;
        uint4 v = *reinterpret_cast<const uint4*>(&h[(size_t)s * LD + oct * 8]);
        float a, b;
        unpack2(v.x, a, b); acc[0] = fmaf(a, w, acc[0]); acc[1] = fmaf(b, w, acc[1]);
        unpack2(v.y, a, b); acc[2] = fmaf(a, w, acc[2]); acc[3] = fmaf(b, w, acc[3]);
        unpack2(v.z, a, b); acc[4] = fmaf(a, w, acc[4]); acc[5] = fmaf(b, w, acc[5]);
        unpack2(v.w, a, b); acc[6] = fmaf(a, w, acc[6]); acc[7] = fmaf(b, w, acc[7]);
    }
    uint4 o;
    o.x = (uint)f2bs(acc[0]) | ((uint)f2bs(acc[1]) << 16);
    o.y = (uint)f2bs(acc[2]) | ((uint)f2bs(acc[3]) << 16);
    o.z = (uint)f2bs(acc[4]) | ((uint)f2bs(acc[5]) << 16);
    o.w = (uint)f2bs(acc[6]) | ((uint)f2bs(acc[7]) << 16);
    *reinterpret_cast<uint4*>(&agg[(size_t)node * LD + oct * 8]) = o;
}

// ---------------- bf16 MFMA GEMM: C = A @ Wt^T (+bias)(+relu), bf16 out ----------------
template <int KI, int LDA, int KO, int LDC, bool BIASRELU>
__global__ __launch_bounds__(256) void gemm_mfma(const ushort* __restrict__ A,
                                                 const ushort* __restrict__ Bt,
                                                 const float* __restrict__ bias,
                                                 ushort* __restrict__ C, int n) {
    __shared__ ushort sA[64][40];
    __shared__ ushort sB[64][40];
    const int t = threadIdx.x;
    const int row0 = blockIdx.x * 64;
    const int col0 = blockIdx.y * 64;
    const int wid = t >> 6, lane = t & 63;
    const int wr = wid >> 1, wc = wid & 1;
    const int lrow = lane & 15;
    const int kgrp = lane >> 4;
    const int srr = t >> 2;      // staging row 0..63
    const int skq = t & 3;       // staging k-octet
    f32x4 acc[2][2];
#pragma unroll
    for (int i = 0; i < 2; ++i)
#pragma unroll
        for (int j = 0; j < 2; ++j) acc[i][j] = (f32x4)0.f;

    const int nk = (KI + 31) / 32;
    for (int ks = 0; ks < nk; ++ks) {
        const int kbase = ks * 32 + skq * 8;
        {   // stage A tile (64 rows x 32 k)
            int grow = row0 + srr;
            uint4 v = {0, 0, 0, 0};
            if (grow < n && kbase < LDA)
                v = *reinterpret_cast<const uint4*>(&A[(size_t)grow * LDA + kbase]);
            *reinterpret_cast<uint4*>(&sA[srr][skq * 8]) = v;
        }
        {   // stage B tile (64 cols x 32 k)
            int gcol = col0 + srr;
            uint4 v = {0, 0, 0, 0};
            if (gcol < KO && kbase < LDA)
                v = *reinterpret_cast<const uint4*>(&Bt[(size_t)gcol * LDA + kbase]);
            *reinterpret_cast<uint4*>(&sB[srr][skq * 8]) = v;
        }
        __syncthreads();
        s16x8 a0 = *reinterpret_cast<const s16x8*>(&sA[wr * 32 + lrow][kgrp * 8]);
        s16x8 a1 = *reinterpret_cast<const s16x8*>(&sA[wr * 32 + 16 + lrow][kgrp * 8]);
        s16x8 b0 = *reinterpret_cast<const s16x8*>(&sB[wc * 32 + lrow][kgrp * 8]);
        s16x8 b1 = *reinterpret_cast<const s16x8*>(&sB[wc * 32 + 16 + lrow][kgrp * 8]);
        acc[0][0] = __builtin_amdgcn_mfma_f32_16x16x32_bf16(a0, b0, acc[0][0], 0, 0, 0);
        acc[0][1] = __builtin_amdgcn_mfma_f32_16x16x32_bf16(a0, b1, acc[0][1], 0, 0, 0);
        acc[1][0] = __builtin_amdgcn_mfma_f32_16x16x32_bf16(a1, b0, acc[1][0], 0, 0, 0);
        acc[1][1] = __builtin_amdgcn_mfma_f32_16x16x32_bf16(a1, b1, acc[1][1], 0, 0, 0);
        __syncthreads();
    }
#pragma unroll
    for (int fr = 0; fr < 2; ++fr)
#pragma unroll
        for (int fc = 0; fc < 2; ++fc)
#pragma unroll
            for (int r = 0; r < 4; ++r) {
                int row = row0 + wr * 32 + fr * 16 + kgrp * 4 + r;
                int col = col0 + wc * 32 + fc * 16 + lrow;
                if (row < n && col < LDC) {
                    float v = acc[fr][fc][r];
                    ushort o = 0;
                    if (col < KO) {
                        if (BIASRELU) v = fmaxf(v + bias[col], 0.f);
                        o = f2bs(v);
                    }
                    C[(size_t)row * LDC + col] = o;
                }
            }
}

// ---------------- segment max pool (batch segments) ----------------
__global__ void seg_max(const ushort* __restrict__ h, const int* __restrict__ bptr,
                        float* __restrict__ g) {
    int b = blockIdx.x;
    int f = threadIdx.x;
    if (f >= 312) return;
    int n0 = bptr[b], n1 = bptr[b + 1];
    float m = -INFINITY;
    for (int n = n0; n < n1; ++n) m = fmaxf(m, b2f(h[(size_t)n * 312 + f]));
    g[(size_t)b * 312 + f] = m;
}

// ---------------- head GEMM: K-split, 32x64 tile, fp32 partials ----------------
template <int KI, int KO, int KS>
__global__ __launch_bounds__(256) void gemm_head(const float* __restrict__ A,
                                                 const float* __restrict__ W,
                                                 float* __restrict__ partial, int n) {
    __shared__ float sA[16][34];
    __shared__ float sW[16][68];
    const int t = threadIdx.x;
    const int row0 = blockIdx.x * 32;
    const int col0 = blockIdx.y * 64;
    const int z = blockIdx.z;
    const int kbeg = z * KS;
    const int kend = min(KI, kbeg + KS);
    const int r0 = (t >> 4) * 2;   // 0..30 (even)
    const int c0 = (t & 15) * 4;   // 0..60 (quad)
    float acc[2][4] = {};
    for (int k0 = kbeg; k0 < kend; k0 += 16) {
        {   // stage A: 32 rows x 16 k
            int row = t >> 3, kk = (t & 7) * 2;
            int grow = row0 + row;
#pragma unroll
            for (int j = 0; j < 2; ++j) {
                float v = 0.f;
                if (grow < n && (k0 + kk + j) < kend) v = A[(size_t)grow * KI + k0 + kk + j];
                sA[kk + j][row] = v;
            }
        }
        {   // stage W: 16 k x 64 cols
            int kk = t >> 4, cc = (t & 15) * 4;
#pragma unroll
            for (int j = 0; j < 4; ++j) {
                float v = 0.f;
                if ((k0 + kk) < kend) v = W[(size_t)(k0 + kk) * KO + col0 + cc + j];
                sW[kk][cc + j] = v;
            }
        }
        __syncthreads();
#pragma unroll 8
        for (int k = 0; k < 16; ++k) {
            float2 a = *reinterpret_cast<const float2*>(&sA[k][r0]);
            float4 w = *reinterpret_cast<const float4*>(&sW[k][c0]);
            acc[0][0] = fmaf(a.x, w.x, acc[0][0]); acc[0][1] = fmaf(a.x, w.y, acc[0][1]);
            acc[0][2] = fmaf(a.x, w.z, acc[0][2]); acc[0][3] = fmaf(a.x, w.w, acc[0][3]);
            acc[1][0] = fmaf(a.y, w.x, acc[1][0]); acc[1][1] = fmaf(a.y, w.y, acc[1][1]);
            acc[1][2] = fmaf(a.y, w.z, acc[1][2]); acc[1][3] = fmaf(a.y, w.w, acc[1][3]);
        }
        __syncthreads();
    }
#pragma unroll
    for (int ri = 0; ri < 2; ++ri) {
        int row = row0 + r0 + ri;
        if (row >= n) continue;
        *reinterpret_cast<float4*>(&partial[((size_t)z * n + row) * KO + col0 + c0]) =
            make_float4(acc[ri][0], acc[ri][1], acc[ri][2], acc[ri][3]);
    }
}

// sum partials over splits + bias (+relu), scatter into C[row*ldc + col_off + col]
template <int NS, bool RELU>
__global__ void head_reduce(const float* __restrict__ partial, const float* __restrict__ bias,
                            float* __restrict__ C, int n, int KO, int ldc, int col_off) {
    int j = blockIdx.x * blockDim.x + threadIdx.x;
    if (j >= n * KO) return;
    int row = j / KO, col = j % KO;
    float acc = bias[col];
#pragma unroll
    for (int s = 0; s < NS; ++s) acc += partial[((size_t)s * n + row) * KO + col];
    if (RELU) acc = fmaxf(acc, 0.f);
    C[(size_t)row * ldc + col_off + col] = acc;
}

// ---------------- Conv1d as implicit GEMM, K-split ----------------
__global__ __launch_bounds__(256) void conv_gemm(const float* __restrict__ T,
                                                 const float* __restrict__ Kxt,
                                                 float* __restrict__ partial) {
    __shared__ float sA[32][66];
    __shared__ float sW[32][36];
    const int t = threadIdx.x;
    const int row0 = blockIdx.x * 64;
    const int split = blockIdx.y;
    const int kbeg = split * CONV_KCHUNK;
    const int kend = min(6000, kbeg + CONV_KCHUNK);
    const int r0 = (t >> 3) * 2;   // row pair (even)
    const int c0 = (t & 7) * 4;    // col quad
    float acc[2][4] = {};
    for (int k0 = kbeg; k0 < kend; k0 += 32) {
        {   // stage A: thread -> row rr, k-octet kq   (kb is a multiple of 8)
            int rr = t >> 2, kq = t & 3;
            int grow = row0 + rr;                 // < 6144 always
            int b = grow / 12, h = grow % 12;
            int kb = k0 + kq * 8;
            int i = kb >> 3;
            const float* tp = &T[(size_t)b * 14250 + (size_t)i * 19 + h];
#pragma unroll
            for (int j = 0; j < 8; ++j)
                sA[kq * 8 + j][rr] = (kb + j < kend) ? tp[j] : 0.f;
        }
        {   // stage B: thread -> k = t&31, o-quad (t>>5)*4
            int kk = t & 31, ob = (t >> 5) * 4;
            int gk = k0 + kk;
#pragma unroll
            for (int j = 0; j < 4; ++j)
                sW[kk][ob + j] = (gk < kend) ? Kxt[(size_t)(ob + j) * 6000 + gk] : 0.f;
        }
        __syncthreads();
#pragma unroll 8
        for (int k = 0; k < 32; ++k) {
            float2 a = *reinterpret_cast<const float2*>(&sA[k][r0]);
            float4 w = *reinterpret_cast<const float4*>(&sW[k][c0]);
            acc[0][0] = fmaf(a.x, w.x, acc[0][0]); acc[0][1] = fmaf(a.x, w.y, acc[0][1]);
            acc[0][2] = fmaf(a.x, w.z, acc[0][2]); acc[0][3] = fmaf(a.x, w.w, acc[0][3]);
            acc[1][0] = fmaf(a.y, w.x, acc[1][0]); acc[1][1] = fmaf(a.y, w.y, acc[1][1]);
            acc[1][2] = fmaf(a.y, w.z, acc[1][2]); acc[1][3] = fmaf(a.y, w.w, acc[1][3]);
        }
        __syncthreads();
    }
#pragma unroll
    for (int ri = 0; ri < 2; ++ri) {
        int row = row0 + r0 + ri;
        int b = row / 12, h = row % 12;
#pragma unroll
        for (int j = 0; j < 4; ++j)
            partial[(((size_t)split * NBATCH + b) * 32 + (c0 + j)) * 12 + h] = acc[ri][j];
    }
}

__global__ void conv_reduce(const float* __restrict__ partial, const float* __restrict__ bxt,
                            float* __restrict__ convb) {
    int j = blockIdx.x * blockDim.x + threadIdx.x;
    if (j >= NBATCH * 384) return;
    int b = j / 384, rem = j % 384;
    int o = rem / 12, h = rem % 12;
    float acc = bxt[o];
#pragma unroll
    for (int s = 0; s < CONV_KSPLIT; ++s)
        acc += partial[(((size_t)s * NBATCH + b) * 32 + o) * 12 + h];
    convb[j] = acc;
}

// ---------------- final [512,512] @ [512,1] ----------------
__global__ void final_out(const float* __restrict__ f2, const float* __restrict__ Wo,
                          const float* __restrict__ bo, float* __restrict__ out) {
    int row = blockIdx.x * (blockDim.x / 64) + (threadIdx.x / 64);
    int lane = threadIdx.x & 63;
    if (row >= NBATCH) return;
    float acc = 0.f;
    for (int k = lane; k < 512; k += 64) acc = fmaf(f2[(size_t)row * 512 + k], Wo[k], acc);
#pragma unroll
    for (int off = 32; off > 0; off >>= 1) acc += __shfl_down(acc, off);
    if (lane == 0) out[row] = acc + bo[0];
}

extern "C" void kernel_launch(void* const* d_in, const int* in_sizes, int n_in,
                              void* d_out, int out_size, void* d_ws, size_t ws_size,
                              hipStream_t stream) {
    (void)in_sizes; (void)n_in; (void)out_size; (void)ws_size;
    const float* x     = (const float*)d_in[0];
    const int*   ei    = (const int*)d_in[1];
    const int*   batch = (const int*)d_in[2];
    const float* T     = (const float*)d_in[3];
    const float* W1 = (const float*)d_in[4];   const float* b1 = (const float*)d_in[5];
    const float* W2 = (const float*)d_in[6];   const float* b2 = (const float*)d_in[7];
    const float* W3 = (const float*)d_in[8];   const float* b3 = (const float*)d_in[9];
    const float* Wg1 = (const float*)d_in[10]; const float* bg1 = (const float*)d_in[11];
    const float* Wg2 = (const float*)d_in[12]; const float* bg2 = (const float*)d_in[13];
    const float* Kxt = (const float*)d_in[14]; const float* bxt = (const float*)d_in[15];
    const float* Wxt = (const float*)d_in[16]; const float* bxt2 = (const float*)d_in[17];
    const float* Wf1 = (const float*)d_in[18]; const float* bf1 = (const float*)d_in[19];
    const float* Wf2 = (const float*)d_in[20]; const float* bf2 = (const float*)d_in[21];
    const float* Wo = (const float*)d_in[22];  const float* bo = (const float*)d_in[23];
    const int* src = ei;
    const int* dst = ei + N_EDGESC;

    char* ws = (char*)d_ws;
    size_t off = 0;
    auto alloc = [&](size_t bytes) -> void* {
        void* p = ws + off;
        off += (bytes + 255) & ~(size_t)255;
        return p;
    };
    // ~138 MB total
    int*   deg      = (int*)alloc((size_t)N_NODESC * 4);
    float* dinv     = (float*)alloc((size_t)N_NODESC * 4);
    int*   row_ptr  = (int*)alloc((size_t)(N_NODESC + 1) * 4);
    int*   fillc    = (int*)alloc((size_t)N_NODESC * 4);
    int*   csr_src  = (int*)alloc((size_t)N_EDGESC * 4);
    int*   csums    = (int*)alloc((size_t)4096 * 4);
    int*   bptr     = (int*)alloc((size_t)(NBATCH + 1) * 4);
    float* g0       = (float*)alloc((size_t)NBATCH * 312 * 4);
    float* g1       = (float*)alloc((size_t)NBATCH * 1024 * 4);
    float* convb    = (float*)alloc((size_t)NBATCH * 384 * 4);
    float* xc       = (float*)alloc((size_t)NBATCH * 256 * 4);
    float* f1       = (float*)alloc((size_t)NBATCH * 1024 * 4);
    float* f2       = (float*)alloc((size_t)NBATCH * 512 * 4);
    float* cpart    = (float*)alloc((size_t)CONV_KSPLIT * NBATCH * 32 * 12 * 4);
    float* hpart    = (float*)alloc((size_t)8 * NBATCH * 128 * 4);  // 2MB: all head splits fit
    ushort* xbf     = (ushort*)alloc((size_t)N_NODESC * 80 * 2);   // x (80) -> later h1 (80)
    ushort* aggbuf  = (ushort*)alloc((size_t)N_NODESC * 160 * 2);  // agg1/2 (80), agg3 (160)
    ushort* hbuf    = (ushort*)alloc((size_t)N_NODESC * 312 * 2);  // h2 (160), h3 (312)
    ushort* Wt1     = (ushort*)alloc((size_t)78 * 80 * 2);
    ushort* Wt2     = (ushort*)alloc((size_t)156 * 80 * 2);
    ushort* Wt3     = (ushort*)alloc((size_t)312 * 160 * 2);
    float* out      = (float*)d_out;

    const int TPB = 256;

    // ---- graph structure ----
    zero_ints<<<divup(N_NODESC, TPB), TPB, 0, stream>>>(deg, N_NODESC);
    count_deg<<<divup(N_EDGESC, TPB), TPB, 0, stream>>>(dst, deg, N_EDGESC);
    compute_dinv<<<divup(N_NODESC, TPB), TPB, 0, stream>>>(deg, dinv, N_NODESC);
    int nchunks = divup(N_NODESC, SCAN_CHUNK);
    scan_chunks<<<nchunks, 256, 0, stream>>>(deg, row_ptr, csums, N_NODESC);
    scan_sums<<<1, 64, 0, stream>>>(csums, nchunks);
    finalize_rowptr<<<divup(N_NODESC, TPB), TPB, 0, stream>>>(row_ptr, csums, fillc, N_NODESC, N_EDGESC);
    fill_csr<<<divup(N_EDGESC, TPB), TPB, 0, stream>>>(src, dst, fillc, csr_src, N_EDGESC);
    build_batch_ptr<<<divup(N_NODESC, TPB), TPB, 0, stream>>>(batch, bptr, N_NODESC, NBATCH);

    // ---- bf16 conversions ----
    convert_x_bf16<<<divup(N_NODESC * 80, TPB), TPB, 0, stream>>>(x, xbf, N_NODESC, 78, 80);
    transpose_w_bf16<<<divup(78 * 80, TPB), TPB, 0, stream>>>(W1, Wt1, 78, 78, 80);
    transpose_w_bf16<<<divup(156 * 80, TPB), TPB, 0, stream>>>(W2, Wt2, 78, 156, 80);
    transpose_w_bf16<<<divup(312 * 160, TPB), TPB, 0, stream>>>(W3, Wt3, 156, 312, 160);

    // ---- GCN layer 1: agg(x) -> gemm+bias+relu -> h1 (LD 80) ----
    gcn_gather_vec<80><<<divup(N_NODESC * 10, TPB), TPB, 0, stream>>>(
        xbf, row_ptr, csr_src, dinv, aggbuf, N_NODESC);
    gemm_mfma<78, 80, 78, 80, true><<<dim3(divup(N_NODESC, 64), 2), 256, 0, stream>>>(
        aggbuf, Wt1, b1, xbf, N_NODESC);   // h1 overwrites xbf (x dead)

    // ---- GCN layer 2: agg(h1) -> gemm -> h2 (LD 160) ----
    gcn_gather_vec<80><<<divup(N_NODESC * 10, TPB), TPB, 0, stream>>>(
        xbf, row_ptr, csr_src, dinv, aggbuf, N_NODESC);
    gemm_mfma<78, 80, 156, 160, true><<<dim3(divup(N_NODESC, 64), 3), 256, 0, stream>>>(
        aggbuf, Wt2, b2, hbuf, N_NODESC);

    // ---- GCN layer 3: agg(h2) -> gemm -> h3 (LD 312) ----
    gcn_gather_vec<160><<<divup(N_NODESC * 20, TPB), TPB, 0, stream>>>(
        hbuf, row_ptr, csr_src, dinv, aggbuf, N_NODESC);
    gemm_mfma<156, 160, 312, 312, true><<<dim3(divup(N_NODESC, 64), 5), 256, 0, stream>>>(
        aggbuf, Wt3, b3, hbuf, N_NODESC);

    // ---- global max pool ----
    seg_max<<<NBATCH, 320, 0, stream>>>(hbuf, bptr, g0);

    // ---- graph head: g1 = relu(g0 @ Wg1 + bg1) ----
    gemm_head<312, 1024, 312><<<dim3(16, 16, 1), 256, 0, stream>>>(g0, Wg1, hpart, NBATCH);
    head_reduce<1, true><<<divup(NBATCH * 1024, TPB), TPB, 0, stream>>>(
        hpart, bg1, g1, NBATCH, 1024, 1024, 0);
    // xc[:, :128] = g1 @ Wg2 + bg2
    gemm_head<1024, 128, 128><<<dim3(16, 2, 8), 256, 0, stream>>>(g1, Wg2, hpart, NBATCH);
    head_reduce<8, false><<<divup(NBATCH * 128, TPB), TPB, 0, stream>>>(
        hpart, bg2, xc, NBATCH, 128, 256, 0);

    // ---- protein branch: implicit-GEMM conv ----
    conv_gemm<<<dim3(6144 / 64, CONV_KSPLIT), 256, 0, stream>>>(T, Kxt, cpart);
    conv_reduce<<<divup(NBATCH * 384, TPB), TPB, 0, stream>>>(cpart, bxt, convb);
    // xc[:, 128:] = convb @ Wxt + bxt2
    gemm_head<384, 128, 48><<<dim3(16, 2, 8), 256, 0, stream>>>(convb, Wxt, hpart, NBATCH);
    head_reduce<8, false><<<divup(NBATCH * 128, TPB), TPB, 0, stream>>>(
        hpart, bxt2, xc, NBATCH, 128, 256, 128);

    // ---- fusion MLP ----
    gemm_head<256, 1024, 256><<<dim3(16, 16, 1), 256, 0, stream>>>(xc, Wf1, hpart, NBATCH);
    head_reduce<1, true><<<divup(NBATCH * 1024, TPB), TPB, 0, stream>>>(
        hpart, bf1, f1, NBATCH, 1024, 1024, 0);
    gemm_head<1024, 512, 512><<<dim3(16, 8, 2), 256, 0, stream>>>(f1, Wf2, hpart, NBATCH);
    head_reduce<2, true><<<divup(NBATCH * 512, TPB), TPB, 0, stream>>>(
        hpart, bf2, f2, NBATCH, 512, 512, 0);
    final_out<<<divup(NBATCH, 4), 256, 0, stream>>>(f2, Wo, bo, out);
}